// Round 9
// baseline (314.662 us; speedup 1.0000x reference)
//
#include <hip/hip_runtime.h>

// B=4, T=2048, D=1024, fp32 in/out, bf16-tolerance threshold.
// Algebra: out = softmax(QK^T/32)@V@Wh + bh = P_norm@(x@(Wv@Wh)) + (bv@Wh + bh).
// Pipeline: prep -> Wvh^T small GEMM (128^2 core) -> gemv bhh -> fused QKV GEMM
//   -> scores GEMM (P'=exp(s)*mask bf16 + atomic row-sums) -> recip_sums ->
//   PV GEMM split-K2 -> combine_upper.
//
// R9 core: BM3=128 x BN3=256, BK=64, 512 thr (8 waves: wm=wave&1 M-half of 64
//   rows, wn=wave>>1 N-quarter of 64 cols), per-wave 64x64 -> acc[4][4].
//   WHY: grid quantization was the measured loss. 256^2 tiles: step3 = 384
//   blocks @1/CU = 1.5 rounds (25% tail idle ~18us); step4 = 144 active of
//   256 (44% CUs idle). 128x256: step3 = 768 blocks = EXACTLY 3.0 rounds;
//   step4 = 288 active half-size blocks = 1.125 rounds.
//   Register budget (R2/R4 lesson: 2 waves/SIMD -> HARD 256 regs/wave):
//   acc 64 + 16 frags 64 + addressing ~45 = ~175, comfortable.
//   LDS 96KB (2dbuf x (A 16K + B 32K)) -> 1 block/CU, 2 waves/SIMD.
// Schedule: 2 phases/K-tile, ONE barrier each = 1 barrier per 16-MFMA
//   cluster — the cadence R6/R7 measured optimal (8/4/2 barriers per 64
//   MFMA = 81/70.5/82us). One-phase-ahead reads (WAR on frag arrays
//   resolves at MFMA issue, in-order issue):
//   P0: MFMA af*bg0 (cols q0); tail read bg1<-q1(t); SBAR.
//   P1: MFMA af*bg1 (cols q1); tail stage A(t+2)+B(t+2) into buf[cur]
//       (6 gload_lds; af/bg1-reads 1 barrier prior — R6-validated margin);
//       WAITV6 drains t+1's 6 loads (t+2's stay in flight — never vmcnt(0)
//       in steady state); SBAR publishes t+1 residency cross-wave; tail
//       read af<-A(t+1), bg0<-q0(t+1) from buf[cur^1].
// XCD swizzle (T1): SALU-only, compile-time GX,GY == ACTUAL grid dims
//   (R5 bug: mismatch -> non-bijective -> wrong results).
//   step3 (12,64), step4 (8,16), step5 (8,16).

typedef __attribute__((ext_vector_type(8)))  short short8;     // MFMA A/B frag
typedef __attribute__((ext_vector_type(4)))  float f4;         // MFMA 16x16 C/D

#define BM 128
#define BN 128
#define BK 64
#define BM3 128
#define BN3 256

// flag bits
#define F_OBF    1     // out bf16
#define F_SKIP   2     // causal tile-skip
#define F_KLIM   4     // causal K-limit
#define F_REVY   8     // reverse-y dispatch
#define F_VSPL   16    // V-split transposed write (n0>=vsplit -> C2)
#define F_RSCL   32    // epilogue * rowsums[row] (rowsums pre-inverted)
#define F_EXP    64    // exp + causal-mask epilogue
#define F_RSUM   128   // atomic row-sum accumulate (with F_EXP)
#define F_SPLITK 256   // split-K2 at k=1024 (PV); split1 -> C2 fp32 partial

#define WAITV6() asm volatile("s_waitcnt vmcnt(6)" ::: "memory")
#define WAITV8() asm volatile("s_waitcnt vmcnt(8)" ::: "memory")
#define WAITV0() asm volatile("s_waitcnt vmcnt(0)" ::: "memory")
#define SBAR()   __builtin_amdgcn_s_barrier()
#define PRIO1()  __builtin_amdgcn_s_setprio(1)
#define PRIO0()  __builtin_amdgcn_s_setprio(0)

__device__ inline unsigned short f2bf(float f) {
    union { float f; unsigned u; } c; c.f = f;
    unsigned u = c.u;
    return (unsigned short)((u + 0x7fffu + ((u >> 16) & 1u)) >> 16);  // RNE
}
__device__ inline float bf2f(unsigned short u) {
    union { unsigned u; float f; } c; c.u = ((unsigned)u) << 16;
    return c.f;
}
__device__ inline void gload16(const void* g, void* l) {
    __builtin_amdgcn_global_load_lds(
        (const __attribute__((address_space(1))) void*)g,
        (__attribute__((address_space(3))) void*)l,
        16, 0, 0);
}

// ---------------------------------------------------------------------------
// OLD 128x128 core (kept for the small Wvh^T GEMM only).
// ---------------------------------------------------------------------------
template<int FLAGS>
__global__ __launch_bounds__(256)
void gemm_bt(const unsigned short* __restrict__ A,
             const unsigned short* __restrict__ Bt,
             void* __restrict__ C,
             const float* __restrict__ bias,
             int M, int N, int K, int lda, int ldb, int ldc,
             long sA, long sB, long sC,
             float scale,
             unsigned short* __restrict__ C2, long sC2, int Tv, int vsplit,
             float* __restrict__ rowsums)
{
    const int b = blockIdx.z;
    A  += (long)b * sA;
    Bt += (long)b * sB;

    int by = blockIdx.y;
    if (FLAGS & F_REVY) by = gridDim.y - 1 - by;
    const int m0 = by * BM;
    const int n0 = blockIdx.x * BN;

    const int kt1 = K / BK;

    __shared__ unsigned short As[BM * BK];   // 16 KB
    __shared__ unsigned short Bs[BN * BK];   // 16 KB

    const int tid  = threadIdx.x;
    const int lane = tid & 63;
    const int wave = tid >> 6;
    const int wm   = wave & 1;
    const int wn   = wave >> 1;
    const int lrow = lane & 15;
    const int quad = lane >> 4;

    f4 acc[4][4];
#pragma unroll
    for (int i = 0; i < 4; ++i)
#pragma unroll
        for (int j = 0; j < 4; ++j) acc[i][j] = (f4)0.0f;

    const int srow = tid >> 3;
    const int gco  = ((tid & 7) ^ (srow & 7)) << 3;
    const int rdsl = (lrow & 7);

    for (int kt = 0; kt < kt1; ++kt) {
        const int k0 = kt * BK;
#pragma unroll
        for (int d = 0; d < 4; ++d) {
            const int row = d * 32 + srow;
            const unsigned short* ga = A  + (long)(m0 + row) * lda + k0 + gco;
            const unsigned short* gb = Bt + (long)(n0 + row) * ldb + k0 + gco;
            const int ldsoff = (d * 256 + wave * 64) * 16;
            gload16(ga, (char*)As + ldsoff);
            gload16(gb, (char*)Bs + ldsoff);
        }
        __syncthreads();

#pragma unroll
        for (int ks = 0; ks < 2; ++ks) {
            const int slot = ((ks * 4 + quad) ^ rdsl) << 3;
            short8 af[4], bfr[4];
#pragma unroll
            for (int i = 0; i < 4; ++i) {
                af[i]  = *(const short8*)(As + (wm * 64 + i * 16 + lrow) * BK + slot);
                bfr[i] = *(const short8*)(Bs + (wn * 64 + i * 16 + lrow) * BK + slot);
            }
#pragma unroll
            for (int i = 0; i < 4; ++i)
#pragma unroll
                for (int j = 0; j < 4; ++j)
                    acc[i][j] = __builtin_amdgcn_mfma_f32_16x16x32_bf16(
                        af[i], bfr[j], acc[i][j], 0, 0, 0);
        }
        __syncthreads();
    }

    const int row0 = m0 + wm * 64 + quad * 4;
    const int col0 = n0 + wn * 64 + lrow;

    float bj[4];
#pragma unroll
    for (int j = 0; j < 4; ++j) bj[j] = bias ? bias[col0 + j * 16] : 0.0f;

    unsigned short* Cb = (unsigned short*)C;
    float*          Cf = (float*)C;
    const long cbase = (long)b * sC;

#pragma unroll
    for (int i = 0; i < 4; ++i) {
#pragma unroll
        for (int j = 0; j < 4; ++j) {
            const int col = col0 + j * 16;
#pragma unroll
            for (int r = 0; r < 4; ++r) {
                const int row = row0 + i * 16 + r;
                float v = acc[i][j][r] * scale + bj[j];
                const long off = cbase + (long)row * ldc + col;
                if (FLAGS & F_OBF) Cb[off] = f2bf(v);
                else               Cf[off] = v;
            }
        }
    }
}

// ---------------------------------------------------------------------------
// 128x256 8-wave 2-phase core helpers
// ---------------------------------------------------------------------------
// read the wave's full 64-row A slice (8 frags)
__device__ inline void lda_w(short8 (&af)[8], const unsigned short* Asb,
                             int wm, int lrow, int quad, int rdsl)
{
#pragma unroll
    for (int i = 0; i < 4; ++i)
#pragma unroll
        for (int ks = 0; ks < 2; ++ks)
            af[i * 2 + ks] = *(const short8*)(
                Asb + (wm * 64 + i * 16 + lrow) * BK
                    + (((ks * 4 + quad) ^ rdsl) << 3));
}

// read one 32-col B quarter-half (4 frags)
template<int QB>
__device__ inline void ldb_q(short8 (&bq)[4], const unsigned short* Bsb,
                             int wn, int lrow, int quad, int rdsl)
{
#pragma unroll
    for (int j = 0; j < 2; ++j)
#pragma unroll
        for (int ks = 0; ks < 2; ++ks)
            bq[j * 2 + ks] = *(const short8*)(
                Bsb + (wn * 64 + QB * 32 + j * 16 + lrow) * BK
                    + (((ks * 4 + quad) ^ rdsl) << 3));
}

// 16 MFMA: full A slice x one B half -> cols CJ..CJ+1, ks-outer
template<int CJ>
__device__ inline void mfma16(f4 (&acc)[4][4], const short8 (&a)[8],
                              const short8 (&b)[4])
{
#pragma unroll
    for (int ks = 0; ks < 2; ++ks)
#pragma unroll
        for (int i = 0; i < 4; ++i)
#pragma unroll
            for (int j = 0; j < 2; ++j)
                acc[i][CJ + j] = __builtin_amdgcn_mfma_f32_16x16x32_bf16(
                    a[i * 2 + ks], b[j * 2 + ks], acc[i][CJ + j], 0, 0, 0);
}

// stage a (ND*64)x64 K-tile of ONE matrix: ND gload_lds (w=16) per thread
template<int ND>
__device__ inline void stage_mat(const unsigned short* __restrict__ Row,
                                 int k0, unsigned short* Ls, int ld, int tid)
{
    const int srow = tid >> 3;                       // row = d*64 + srow
    const int gco  = ((tid & 7) ^ (srow & 7)) << 3;  // pre-swizzled global chunk
    const int wave = tid >> 6;
#pragma unroll
    for (int d = 0; d < ND; ++d) {
        const int row = d * 64 + srow;
        const int ldsoff = (d * 512 + wave * 64) * 16;   // bytes, wave-uniform
        gload16(Row + (long)row * ld + k0 + gco, (char*)Ls + ldsoff);
    }
}

// ---------------------------------------------------------------------------
// C = A[M,K] @ Bt[N,K]^T, bf16 in, fp32/bf16 out. 128x256 2-phase core.
// ktiles >= 2 at every call site. GX,GY: compile-time grid dims for the
// SALU-only XCD swizzle (0 = off). MUST equal launch grid dims (bijectivity).
// ---------------------------------------------------------------------------
template<int FLAGS, int GX = 0, int GY = 0>
__global__ __launch_bounds__(512)
void gemmw(const unsigned short* __restrict__ A,
           const unsigned short* __restrict__ Bt,
           void* __restrict__ C,
           const float* __restrict__ bias,
           int M, int N, int K, int lda, int ldb, int ldc,
           long sA, long sB, long sC,
           float scale,
           unsigned short* __restrict__ C2, long sC2, int Tv, int vsplit,
           float* __restrict__ rowsums)
{
    const int b = blockIdx.z;
    A  += (long)b * sA;
    Bt += (long)b * sB;
    if (FLAGS & (F_RSCL | F_RSUM)) rowsums += (long)b * M;

    int bxr = blockIdx.x, byr = blockIdx.y;
    if (GX > 0) {
        constexpr int NWG = GX * GY;
        constexpr int Q   = NWG >> 3;
        static_assert((NWG & 7) == 0, "swizzle needs NWG%8==0");
        const int lin  = byr * GX + bxr;
        const int virt = (lin & 7) * Q + (lin >> 3);
        bxr = virt % GX; byr = virt / GX;
    }

    int by = byr;
    if (FLAGS & F_REVY) by = gridDim.y - 1 - by;
    const int m0 = by * BM3;

    int n0, split = 0;
    if (FLAGS & F_SPLITK) {
        const int nbx = N / BN3;
        n0 = (bxr % nbx) * BN3;
        split = bxr / nbx;
        if (split && m0 < 1024) return;
    } else {
        n0 = bxr * BN3;
    }

    if ((FLAGS & F_SKIP) && n0 > m0 + (BM3 - 1)) return;

    int kend = K;
    if (FLAGS & F_KLIM) { int ke = m0 + BM3; kend = ke < K ? ke : K; }
    int kt0 = 0;
    if (FLAGS & F_SPLITK) {
        if (split == 0) { if (kend > 1024) kend = 1024; }
        else            { kt0 = 1024 / BK; }
    }
    const int kt1 = kend / BK;

    // 2 dbuf x (A 16K + B 32K) = 96 KB
    __shared__ unsigned short smA[2][BM3 * BK];
    __shared__ unsigned short smB[2][BN3 * BK];

    const int tid  = threadIdx.x;
    const int lane = tid & 63;
    const int wave = tid >> 6;
    const int wm   = wave & 1;     // 2 M-halves of 64 rows
    const int wn   = wave >> 1;    // 4 N-quarters of 64 cols
    const int lrow = lane & 15;
    const int quad = lane >> 4;
    const int rdsl = lrow & 7;

    f4 acc[4][4];
#pragma unroll
    for (int i = 0; i < 4; ++i)
#pragma unroll
        for (int j = 0; j < 4; ++j) acc[i][j] = (f4)0.0f;

    const unsigned short* Arow = A  + (long)m0 * lda;
    const unsigned short* Brow = Bt + (long)n0 * ldb;
    const int ktiles = kt1 - kt0;   // >= 2 at every call site

    // 16-fragment set: af[8] (full 64-row A slice), bg0/bg1 (32-col B halves)
    short8 af[8], bg0[4], bg1[4];

    // prologue: stage tiles 0,1 (6 loads each); counted drain of tile0
    // (tile1's 6 stay in flight); barrier publishes; read P0 frags.
    stage_mat<2>(Arow, kt0 * BK, smA[0], lda, tid);
    stage_mat<4>(Brow, kt0 * BK, smB[0], ldb, tid);
    stage_mat<2>(Arow, (kt0 + 1) * BK, smA[1], lda, tid);
    stage_mat<4>(Brow, (kt0 + 1) * BK, smB[1], ldb, tid);
    WAITV6();
    SBAR();
    lda_w(af, smA[0], wm, lrow, quad, rdsl);
    ldb_q<0>(bg0, smB[0], wn, lrow, quad, rdsl);

    for (int t = 0; t < ktiles; ++t) {
        const int cur = t & 1;
        const bool s2 = (t + 2 < ktiles);
        const bool rd = (t + 1 < ktiles);

        // P0: MFMA af*bg0 -> cols 0-1; tail-read bg1<-q1(t); SBAR.
        PRIO1(); mfma16<0>(acc, af, bg0); PRIO0();
        ldb_q<1>(bg1, smB[cur], wn, lrow, quad, rdsl);
        SBAR();

        // P1: MFMA af*bg1 -> cols 2-3; tail: stage A(t+2)+B(t+2) into
        //     buf[cur] (af/bg1 reads 1 barrier prior); WAITV6 drains t+1
        //     (t+2's 6 in flight); SBAR publishes; read next tile's frags.
        PRIO1(); mfma16<2>(acc, af, bg1); PRIO0();
        if (s2) {
            stage_mat<2>(Arow, (kt0 + t + 2) * BK, smA[cur], lda, tid);
            stage_mat<4>(Brow, (kt0 + t + 2) * BK, smB[cur], ldb, tid);
            WAITV6();
        } else {
            WAITV0();
        }
        SBAR();
        if (rd) {
            lda_w(af, smA[cur ^ 1], wm, lrow, quad, rdsl);
            ldb_q<0>(bg0, smB[cur ^ 1], wn, lrow, quad, rdsl);
        }
    }

    // epilogue: C/D layout col=lane&15, row=quad*4+reg (m89/m91)
    const int row0 = m0 + wm * 64 + quad * 4;
    const int col0 = n0 + wn * 64 + lrow;

    float bj[4];
#pragma unroll
    for (int j = 0; j < 4; ++j) bj[j] = bias ? bias[col0 + j * 16] : 0.0f;

    if ((FLAGS & F_VSPL) && n0 >= vsplit) {
        // Vh region: write transposed to C2[b][d][t], packed 4 bf16 (8B) stores
        const int bidx  = m0 >> 11;               // T=2048 rows per batch
        const int tloc0 = (m0 & 2047) + wm * 64 + quad * 4;
#pragma unroll
        for (int j = 0; j < 4; ++j) {
            const int d = col0 + j * 16 - vsplit;
            unsigned short* base = C2 + (long)bidx * sC2 + (long)d * Tv;
#pragma unroll
            for (int i = 0; i < 4; ++i) {
                const int tt = tloc0 + i * 16;
                unsigned long long pk = 0;
#pragma unroll
                for (int r = 0; r < 4; ++r) {
                    float v = acc[i][j][r] * scale + bj[j];
                    pk |= (unsigned long long)f2bf(v) << (16 * r);
                }
                *(unsigned long long*)(base + tt) = pk;
            }
        }
        return;
    }

    float inv[16];
    if (FLAGS & F_RSCL) {
#pragma unroll
        for (int i = 0; i < 4; ++i)
#pragma unroll
            for (int r = 0; r < 4; ++r)
                inv[i * 4 + r] = rowsums[row0 + i * 16 + r];  // pre-inverted
    }

    float rs[16];
    if (FLAGS & F_RSUM) {
#pragma unroll
        for (int k = 0; k < 16; ++k) rs[k] = 0.0f;
    }

    unsigned short* Cb = (unsigned short*)C;
    float*          Cf = ((FLAGS & F_SPLITK) && split) ? (float*)C2 : (float*)C;
    const long cbase = (long)b * sC;

#pragma unroll
    for (int i = 0; i < 4; ++i) {
#pragma unroll
        for (int j = 0; j < 4; ++j) {
            const int col = col0 + j * 16;
#pragma unroll
            for (int r = 0; r < 4; ++r) {
                const int row = row0 + i * 16 + r;
                float v = acc[i][j][r] * scale;
                if (FLAGS & F_EXP) { v = __expf(v); if (col > row) v = 0.0f; }
                if (FLAGS & F_RSUM) rs[i * 4 + r] += v;
                if (FLAGS & F_RSCL) v *= inv[i * 4 + r];
                if (!((FLAGS & F_SPLITK) && split)) v += bj[j];
                const long off = cbase + (long)row * ldc + col;
                if (FLAGS & F_OBF) Cb[off] = f2bf(v);
                else               Cf[off] = v;
            }
        }
    }

    if (FLAGS & F_RSUM) {
        // reduce across the 16 col-lanes (lrow bits), then one atomic per row
#pragma unroll
        for (int k = 0; k < 16; ++k) {
            rs[k] += __shfl_xor(rs[k], 1);
            rs[k] += __shfl_xor(rs[k], 2);
            rs[k] += __shfl_xor(rs[k], 4);
            rs[k] += __shfl_xor(rs[k], 8);
        }
        if (lrow == 0) {
#pragma unroll
            for (int i = 0; i < 4; ++i)
#pragma unroll
                for (int r = 0; r < 4; ++r)
                    atomicAdd(&rowsums[row0 + i * 16 + r], rs[i * 4 + r]);
        }
    }
}

// ---------------------------------------------------------------------------
// combine_upper: out[b][1024+..][*] += part[b][1024+..][*]  (float4)
// ---------------------------------------------------------------------------
__global__ void combine_upper(float* __restrict__ out,
                              const float* __restrict__ part)
{
    const long base = ((long)blockIdx.y * 2048 + 1024) * 1024 / 4;  // f4 units
    const long i = base + blockIdx.x * 256 + threadIdx.x;
    f4 a = ((f4*)out)[i];
    f4 bb = ((const f4*)part)[i];
    a.x += bb.x; a.y += bb.y; a.z += bb.z; a.w += bb.w;
    ((f4*)out)[i] = a;
}

// ---------------------------------------------------------------------------
// recip_sums: s[i] = 1/s[i]  (so PV epilogue multiplies instead of divides)
// ---------------------------------------------------------------------------
__global__ void recip_sums(float* __restrict__ s)
{
    const int i = blockIdx.x * 256 + threadIdx.x;
    s[i] = 1.0f / s[i];
}

// ---------------------------------------------------------------------------
// gemv: bhh[m] = dot(Wht[m][:], bv) + bh[m]
// ---------------------------------------------------------------------------
__global__ void gemv_bhh(const unsigned short* __restrict__ Wht,
                         const float* __restrict__ bv,
                         const float* __restrict__ bh,
                         float* __restrict__ bhh)
{
    const int m = blockIdx.x;
    const int tid = threadIdx.x;
    const int lane = tid & 63, wave = tid >> 6;
    __shared__ float red[4];
    const unsigned short* row = Wht + (long)m * 1024;
    float s = 0.0f;
#pragma unroll
    for (int k = 0; k < 4; ++k) {
        const int idx = tid * 4 + k;
        s += bf2f(row[idx]) * bv[idx];
    }
    for (int o = 32; o > 0; o >>= 1) s += __shfl_down(s, o);
    if (lane == 0) red[wave] = s;
    __syncthreads();
    if (tid == 0) bhh[m] = red[0] + red[1] + red[2] + red[3] + bh[m];
}

// ---------------------------------------------------------------------------
// prep: x cast [0,8192) | Wv plain cast [8192,9216) |
//       transposes Wq/Wk/Wh [9216,12288) | biases [12288]
// ---------------------------------------------------------------------------
__global__ void prep(const float* __restrict__ x,
                     const float* __restrict__ Wq, const float* __restrict__ Wk,
                     const float* __restrict__ Wv, const float* __restrict__ Wh,
                     const float* __restrict__ bq, const float* __restrict__ bk,
                     unsigned short* __restrict__ Xbf,
                     unsigned short* __restrict__ Wqkvt,
                     unsigned short* __restrict__ Wht,
                     unsigned short* __restrict__ Wvb,
                     float* __restrict__ bqkv)
{
    __shared__ unsigned short tsh[32][33];
    const int bid = blockIdx.x;
    const int tid = threadIdx.x;

    if (bid < 8192) {                       // cast x
        const int i = bid * 256 + tid;
        f4 v = ((const f4*)x)[i];
        unsigned long long p = (unsigned long long)f2bf(v.x)
                             | ((unsigned long long)f2bf(v.y) << 16)
                             | ((unsigned long long)f2bf(v.z) << 32)
                             | ((unsigned long long)f2bf(v.w) << 48);
        ((unsigned long long*)Xbf)[i] = p;
    } else if (bid < 9216) {                // plain cast Wv
        const int i = (bid - 8192) * 256 + tid;
        f4 v = ((const f4*)Wv)[i];
        unsigned long long p = (unsigned long long)f2bf(v.x)
                             | ((unsigned long long)f2bf(v.y) << 16)
                             | ((unsigned long long)f2bf(v.z) << 32)
                             | ((unsigned long long)f2bf(v.w) << 48);
        ((unsigned long long*)Wvb)[i] = p;
    } else if (bid < 12288) {               // transpose+cast Wq, Wk, Wh
        const int wi = bid - 9216;
        const int w = wi >> 10, tile = wi & 1023;
        const float* src = (w == 0) ? Wq : (w == 1) ? Wk : Wh;
        unsigned short* dst = (w == 0) ? Wqkvt : (w == 1) ? (Wqkvt + 1024 * 1024) : Wht;
        const int c0 = (tile & 31) * 32, r0 = (tile >> 5) * 32;
        const int xx = tid & 31, yy = tid >> 5;
        for (int i = yy; i < 32; i += 8)
            tsh[i][xx] = f2bf(src[(long)(r0 + i) * 1024 + c0 + xx]);
        __syncthreads();
        for (int i = yy; i < 32; i += 8)
            dst[(long)(c0 + i) * 1024 + r0 + xx] = tsh[xx][i];
    } else {                                // biases: Q, K real; Vh third = 0
        const int i = (bid - 12288) * 256 + tid;
        if (i < 1024) { bqkv[i] = bq[i]; bqkv[1024 + i] = bk[i]; bqkv[2048 + i] = 0.0f; }
    }
}

// ---------------------------------------------------------------------------
extern "C" void kernel_launch(void* const* d_in, const int* in_sizes, int n_in,
                              void* d_out, int out_size, void* d_ws, size_t ws_size,
                              hipStream_t stream)
{
    const float* x  = (const float*)d_in[0];
    const float* Wq = (const float*)d_in[1];
    const float* bq = (const float*)d_in[2];
    const float* Wk = (const float*)d_in[3];
    const float* bk = (const float*)d_in[4];
    const float* Wv = (const float*)d_in[5];
    const float* bv = (const float*)d_in[6];
    const float* Wh = (const float*)d_in[7];
    const float* bh = (const float*)d_in[8];
    float* out = (float*)d_out;

    const int  Bb = 4, T = 2048, Dm = 1024;
    const long BT = (long)Bb * T;

    unsigned short* ws = (unsigned short*)d_ws;
    size_t o = 0;
    unsigned short* Xbf   = ws + o; o += (size_t)BT * Dm;         // 16 MB
    unsigned short* Wqkvt = ws + o; o += (size_t)3 * Dm * Dm;     //  6 MB (3rd = Wvh^T)
    unsigned short* Wht   = ws + o; o += (size_t)Dm * Dm;         //  2 MB
    unsigned short* Wvb   = ws + o; o += (size_t)Dm * Dm;         //  2 MB
    float* bqkv = (float*)(ws + o); o += (size_t)3 * Dm * 2;      // 12 KB
    float* bhh  = (float*)(ws + o); o += (size_t)Dm * 2;          //  4 KB
    float* sums = (float*)(ws + o); o += (size_t)BT * 2;          // 32 KB
    unsigned short* QKV   = ws + o; o += (size_t)BT * 3 * Dm;     // 48 MB
    unsigned short* Vt    = ws + o; o += (size_t)BT * Dm;         // 16 MB (Vh^T)
    unsigned short* Pp    = ws + o; o += (size_t)Bb * T * T;      // 32 MB (P' = exp(s))
    float* part = (float*)(ws + o);                               // 32 MB fp32 partial

    const dim3 blk(256);
    const dim3 blk2(512);
    const long sRow3 = (long)T * 3 * Dm;

    // 0. zero row-sum accumulators (32 KB)
    hipMemsetAsync(sums, 0, (size_t)BT * sizeof(float), stream);

    // 1. prep: casts, transposes, biases
    prep<<<12289, blk, 0, stream>>>(x, Wq, Wk, Wv, Wh, bq, bk,
                                    Xbf, Wqkvt, Wht, Wvb, bqkv);

    // 2a. Wvh^T = (Wv@Wh)^T : C[m][n] = sum_k Wht[m][k]*Wvb[n][k] -> bf16
    gemm_bt<F_OBF><<<dim3(Dm / BN, Dm / BM, 1), blk, 0, stream>>>(
        Wht, Wvb, Wqkvt + 2 * Dm * Dm, nullptr, Dm, Dm, Dm, Dm, Dm, Dm,
        0, 0, 0, 1.0f, nullptr, 0, 0, 0, nullptr);

    // 2b. bhh = bv@Wh + bh
    gemv_bhh<<<Dm, blk, 0, stream>>>(Wht, bv, bh, bhh);

    // 3. fused Q/K/Vh projection; Vh third written transposed into Vt
    //    grid (12, 64) = 768 blocks = EXACTLY 3.0 rounds; <12,64> swizzle
    gemmw<F_OBF | F_VSPL, 12, 64>
        <<<dim3(3 * Dm / BN3, BT / BM3, 1), blk2, 0, stream>>>(
        Xbf, Wqkvt, QKV, bqkv, (int)BT, 3 * Dm, Dm, Dm, Dm, 3 * Dm,
        0, 0, 0, 1.0f, Vt, (long)Dm * T, T, 2 * Dm, nullptr);

    // 4. P' = exp(Q@K^T / 32) * mask -> bf16 + atomic row-sums, tile-skip,
    //    rev-y. grid (8, 16, Bb), <8,16> swizzle; 288 active blocks.
    gemmw<F_OBF | F_SKIP | F_REVY | F_EXP | F_RSUM, 8, 16>
        <<<dim3(T / BN3, T / BM3, Bb), blk2, 0, stream>>>(
        QKV, QKV + Dm, Pp, nullptr, T, T, Dm, 3 * Dm, 3 * Dm, T,
        sRow3, sRow3, (long)T * T, 1.0f / 32.0f,
        nullptr, 0, 0, 0, sums);

    // 4b. invert row sums once (PV epilogue multiplies)
    recip_sums<<<dim3((int)(BT / 256)), blk, 0, stream>>>(sums);

    // 5. out = (P' @ Vh^T) * rsum[row] + bhh, split-K2 (split1 -> part)
    //    grid (8, 16, Bb): x = 2*nbx (nbx = 1024/256 = 4); <8,16> swizzle
    gemmw<F_KLIM | F_REVY | F_RSCL | F_SPLITK, 8, 16>
        <<<dim3(2 * Dm / BN3, T / BM3, Bb), blk2, 0, stream>>>(
        Pp, Vt, out, bhh, T, Dm, T, T, T, Dm,
        (long)T * T, (long)Dm * T, (long)T * Dm, 1.0f,
        (unsigned short*)part, 0, 0, 0, sums);

    // 6. out upper rows += part upper rows
    combine_upper<<<dim3(1024, Bb), blk, 0, stream>>>(out, part);
}

// Round 10
// 274.597 us; speedup vs baseline: 1.1459x; 1.1459x over previous
//
#include <hip/hip_runtime.h>

// B=4, T=2048, D=1024, fp32 in/out, bf16-tolerance threshold.
// Algebra: out = softmax(QK^T/32)@V@Wh + bh = P_norm@(x@(Wv@Wh)) + (bv@Wh + bh).
// Pipeline: prep -> Wvh^T small GEMM (128^2 core) -> gemv bhh ->
//   step3a Q,K projection (256^2 core, 256 blocks = EXACTLY 1 round) ->
//   step3b Vh projection -> Vt transposed (128x256 core, 256 blocks = 1 round)
//   -> scores GEMM (256^2; P'=exp(s)*mask bf16 + atomic row-sums) ->
//   recip_sums -> PV GEMM split-K2 (256^2) -> combine_upper.
//
// R10 = R8 (best, 278.6us) + step-3 split by exact-round decomposition:
//   256^2 on the full 8192x3072 plane = 384 blocks = 1.5 rounds (~18us tail
//   idle, measured); Q,K = 8192x2048 = 256 blocks 256^2 (1.0 round) and
//   Vh = 8192x1024 = 256 blocks 128x256 (1.0 round). R9 measured: 128x256
//   everywhere REGRESSES (FETCH +41%, steps4/5 -29us) -> use it ONLY for
//   the Vh sliver; steps 4/5 stay on the 256^2 core (R8 config).
//
// 256^2 core (R6-verified): budget 2 waves/SIMD -> HARD 256 regs/wave;
//   acc[8][4]=128 AGPR + 16 short8 frags (64 VGPR). 4 phases/K-tile, ONE
//   barrier each (ladder measured: 8/4/2 barriers per K-tile = 81/70.5/82us
//   -> 4 optimal; barriers ALIGN the 2 waves/SIMD). One-phase-ahead reads;
//   counted vmcnt, never 0 in steady state.
// 128x256 core (R9-verified): 2 phases/K-tile, 96KB LDS, acc[4][4], WAITV6.
// XCD swizzle (T1): SALU-only, compile-time GX,GY == ACTUAL grid dims
//   (R5 bug: mismatch -> non-bijective -> wrong results).

typedef __attribute__((ext_vector_type(8)))  short short8;     // MFMA A/B frag
typedef __attribute__((ext_vector_type(4)))  float f4;         // MFMA 16x16 C/D

#define BM 128
#define BN 128
#define BK 64
#define BM2 256
#define BN2 256
#define BM3 128
#define BN3 256

// flag bits
#define F_OBF    1     // out bf16
#define F_SKIP   2     // causal tile-skip
#define F_KLIM   4     // causal K-limit
#define F_REVY   8     // reverse-y dispatch
#define F_VSPL   16    // V-split transposed write (n0>=vsplit -> C2)
#define F_RSCL   32    // epilogue * rowsums[row] (rowsums pre-inverted)
#define F_EXP    64    // exp + causal-mask epilogue
#define F_RSUM   128   // atomic row-sum accumulate (with F_EXP)
#define F_SPLITK 256   // split-K2 at k=1024 (PV); split1 -> C2 fp32 partial

#define WAITV4() asm volatile("s_waitcnt vmcnt(4)" ::: "memory")
#define WAITV6() asm volatile("s_waitcnt vmcnt(6)" ::: "memory")
#define WAITV8() asm volatile("s_waitcnt vmcnt(8)" ::: "memory")
#define WAITV0() asm volatile("s_waitcnt vmcnt(0)" ::: "memory")
#define SBAR()   __builtin_amdgcn_s_barrier()
#define PRIO1()  __builtin_amdgcn_s_setprio(1)
#define PRIO0()  __builtin_amdgcn_s_setprio(0)

__device__ inline unsigned short f2bf(float f) {
    union { float f; unsigned u; } c; c.f = f;
    unsigned u = c.u;
    return (unsigned short)((u + 0x7fffu + ((u >> 16) & 1u)) >> 16);  // RNE
}
__device__ inline float bf2f(unsigned short u) {
    union { unsigned u; float f; } c; c.u = ((unsigned)u) << 16;
    return c.f;
}
__device__ inline void gload16(const void* g, void* l) {
    __builtin_amdgcn_global_load_lds(
        (const __attribute__((address_space(1))) void*)g,
        (__attribute__((address_space(3))) void*)l,
        16, 0, 0);
}

// ---------------------------------------------------------------------------
// OLD 128x128 core (kept for the small Wvh^T GEMM only).
// ---------------------------------------------------------------------------
template<int FLAGS>
__global__ __launch_bounds__(256)
void gemm_bt(const unsigned short* __restrict__ A,
             const unsigned short* __restrict__ Bt,
             void* __restrict__ C,
             const float* __restrict__ bias,
             int M, int N, int K, int lda, int ldb, int ldc,
             long sA, long sB, long sC,
             float scale,
             unsigned short* __restrict__ C2, long sC2, int Tv, int vsplit,
             float* __restrict__ rowsums)
{
    const int b = blockIdx.z;
    A  += (long)b * sA;
    Bt += (long)b * sB;

    int by = blockIdx.y;
    if (FLAGS & F_REVY) by = gridDim.y - 1 - by;
    const int m0 = by * BM;
    const int n0 = blockIdx.x * BN;

    const int kt1 = K / BK;

    __shared__ unsigned short As[BM * BK];   // 16 KB
    __shared__ unsigned short Bs[BN * BK];   // 16 KB

    const int tid  = threadIdx.x;
    const int lane = tid & 63;
    const int wave = tid >> 6;
    const int wm   = wave & 1;
    const int wn   = wave >> 1;
    const int lrow = lane & 15;
    const int quad = lane >> 4;

    f4 acc[4][4];
#pragma unroll
    for (int i = 0; i < 4; ++i)
#pragma unroll
        for (int j = 0; j < 4; ++j) acc[i][j] = (f4)0.0f;

    const int srow = tid >> 3;
    const int gco  = ((tid & 7) ^ (srow & 7)) << 3;
    const int rdsl = (lrow & 7);

    for (int kt = 0; kt < kt1; ++kt) {
        const int k0 = kt * BK;
#pragma unroll
        for (int d = 0; d < 4; ++d) {
            const int row = d * 32 + srow;
            const unsigned short* ga = A  + (long)(m0 + row) * lda + k0 + gco;
            const unsigned short* gb = Bt + (long)(n0 + row) * ldb + k0 + gco;
            const int ldsoff = (d * 256 + wave * 64) * 16;
            gload16(ga, (char*)As + ldsoff);
            gload16(gb, (char*)Bs + ldsoff);
        }
        __syncthreads();

#pragma unroll
        for (int ks = 0; ks < 2; ++ks) {
            const int slot = ((ks * 4 + quad) ^ rdsl) << 3;
            short8 af[4], bfr[4];
#pragma unroll
            for (int i = 0; i < 4; ++i) {
                af[i]  = *(const short8*)(As + (wm * 64 + i * 16 + lrow) * BK + slot);
                bfr[i] = *(const short8*)(Bs + (wn * 64 + i * 16 + lrow) * BK + slot);
            }
#pragma unroll
            for (int i = 0; i < 4; ++i)
#pragma unroll
                for (int j = 0; j < 4; ++j)
                    acc[i][j] = __builtin_amdgcn_mfma_f32_16x16x32_bf16(
                        af[i], bfr[j], acc[i][j], 0, 0, 0);
        }
        __syncthreads();
    }

    const int row0 = m0 + wm * 64 + quad * 4;
    const int col0 = n0 + wn * 64 + lrow;

    float bj[4];
#pragma unroll
    for (int j = 0; j < 4; ++j) bj[j] = bias ? bias[col0 + j * 16] : 0.0f;

    unsigned short* Cb = (unsigned short*)C;
    float*          Cf = (float*)C;
    const long cbase = (long)b * sC;

#pragma unroll
    for (int i = 0; i < 4; ++i) {
#pragma unroll
        for (int j = 0; j < 4; ++j) {
            const int col = col0 + j * 16;
#pragma unroll
            for (int r = 0; r < 4; ++r) {
                const int row = row0 + i * 16 + r;
                float v = acc[i][j][r] * scale + bj[j];
                const long off = cbase + (long)row * ldc + col;
                if (FLAGS & F_OBF) Cb[off] = f2bf(v);
                else               Cf[off] = v;
            }
        }
    }
}

// ---------------------------------------------------------------------------
// shared helpers for the 512-thread cores
// ---------------------------------------------------------------------------
// read one 32-col B quarter-half (4 frags)
template<int QB>
__device__ inline void ldb_q(short8 (&bq)[4], const unsigned short* Bsb,
                             int wn, int lrow, int quad, int rdsl)
{
#pragma unroll
    for (int j = 0; j < 2; ++j)
#pragma unroll
        for (int ks = 0; ks < 2; ++ks)
            bq[j * 2 + ks] = *(const short8*)(
                Bsb + (wn * 64 + QB * 32 + j * 16 + lrow) * BK
                    + (((ks * 4 + quad) ^ rdsl) << 3));
}

// stage a (ND*64)x64 K-tile of ONE matrix: ND gload_lds (w=16) per thread
template<int ND>
__device__ inline void stage_mat(const unsigned short* __restrict__ Row,
                                 int k0, unsigned short* Ls, int ld, int tid)
{
    const int srow = tid >> 3;                       // row = d*64 + srow
    const int gco  = ((tid & 7) ^ (srow & 7)) << 3;  // pre-swizzled global chunk
    const int wave = tid >> 6;
#pragma unroll
    for (int d = 0; d < ND; ++d) {
        const int row = d * 64 + srow;
        const int ldsoff = (d * 512 + wave * 64) * 16;   // bytes, wave-uniform
        gload16(Row + (long)row * ld + k0 + gco, (char*)Ls + ldsoff);
    }
}

// --- 256^2 core helpers ---
template<int HA>
__device__ inline void lda_half(short8 (&af)[8], const unsigned short* Asb,
                                int wm, int lrow, int quad, int rdsl)
{
#pragma unroll
    for (int i = 0; i < 4; ++i)
#pragma unroll
        for (int ks = 0; ks < 2; ++ks)
            af[i * 2 + ks] = *(const short8*)(
                Asb + (wm * 128 + HA * 64 + i * 16 + lrow) * BK
                    + (((ks * 4 + quad) ^ rdsl) << 3));
}

// one C-quadrant x K=64: 16 MFMA, ks-outer (8 independent between acc reuse)
template<int RI, int CJ>
__device__ inline void mfma_cl(f4 (&acc)[8][4], const short8 (&a)[8],
                               const short8 (&b)[4])
{
#pragma unroll
    for (int ks = 0; ks < 2; ++ks)
#pragma unroll
        for (int i = 0; i < 4; ++i)
#pragma unroll
            for (int j = 0; j < 2; ++j)
                acc[RI + i][CJ + j] = __builtin_amdgcn_mfma_f32_16x16x32_bf16(
                    a[i * 2 + ks], b[j * 2 + ks], acc[RI + i][CJ + j], 0, 0, 0);
}

// --- 128x256 core helpers ---
// read the wave's full 64-row A slice (8 frags)
__device__ inline void lda_w(short8 (&af)[8], const unsigned short* Asb,
                             int wm, int lrow, int quad, int rdsl)
{
#pragma unroll
    for (int i = 0; i < 4; ++i)
#pragma unroll
        for (int ks = 0; ks < 2; ++ks)
            af[i * 2 + ks] = *(const short8*)(
                Asb + (wm * 64 + i * 16 + lrow) * BK
                    + (((ks * 4 + quad) ^ rdsl) << 3));
}

// 16 MFMA: full A slice x one B half -> cols CJ..CJ+1, ks-outer
template<int CJ>
__device__ inline void mfma16(f4 (&acc)[4][4], const short8 (&a)[8],
                              const short8 (&b)[4])
{
#pragma unroll
    for (int ks = 0; ks < 2; ++ks)
#pragma unroll
        for (int i = 0; i < 4; ++i)
#pragma unroll
            for (int j = 0; j < 2; ++j)
                acc[i][CJ + j] = __builtin_amdgcn_mfma_f32_16x16x32_bf16(
                    a[i * 2 + ks], b[j * 2 + ks], acc[i][CJ + j], 0, 0, 0);
}

// ---------------------------------------------------------------------------
// C = A[M,K] @ Bt[N,K]^T, bf16 in, fp32/bf16 out. 256^2 4-phase core,
// 16-fragment read-rotation pipeline. ktiles >= 2 at every call site.
// GX,GY: compile-time grid dims for SALU-only XCD swizzle (0 = off).
// GX/GY MUST equal the launch grid dims (bijectivity!).
// ---------------------------------------------------------------------------
template<int FLAGS, int GX = 0, int GY = 0>
__global__ __launch_bounds__(512)
void gemm256(const unsigned short* __restrict__ A,
             const unsigned short* __restrict__ Bt,
             void* __restrict__ C,
             const float* __restrict__ bias,
             int M, int N, int K, int lda, int ldb, int ldc,
             long sA, long sB, long sC,
             float scale,
             unsigned short* __restrict__ C2, long sC2, int Tv, int vsplit,
             float* __restrict__ rowsums)
{
    const int b = blockIdx.z;
    A  += (long)b * sA;
    Bt += (long)b * sB;
    if (FLAGS & (F_RSCL | F_RSUM)) rowsums += (long)b * M;

    int bxr = blockIdx.x, byr = blockIdx.y;
    if (GX > 0) {
        constexpr int NWG = GX * GY;
        constexpr int Q   = NWG >> 3;
        static_assert((NWG & 7) == 0, "swizzle needs NWG%8==0");
        const int lin  = byr * GX + bxr;
        const int virt = (lin & 7) * Q + (lin >> 3);
        bxr = virt % GX; byr = virt / GX;
    }

    int by = byr;
    if (FLAGS & F_REVY) by = gridDim.y - 1 - by;
    const int m0 = by * BM2;

    int n0, split = 0;
    if (FLAGS & F_SPLITK) {
        const int nbx = N / BN2;
        n0 = (bxr % nbx) * BN2;
        split = bxr / nbx;
        if (split && m0 < 1024) return;
    } else {
        n0 = bxr * BN2;
    }

    if ((FLAGS & F_SKIP) && n0 > m0 + (BM2 - 1)) return;

    int kend = K;
    if (FLAGS & F_KLIM) { int ke = m0 + BM2; kend = ke < K ? ke : K; }
    int kt0 = 0;
    if (FLAGS & F_SPLITK) {
        if (split == 0) { if (kend > 1024) kend = 1024; }
        else            { kt0 = 1024 / BK; }
    }
    const int kt1 = kend / BK;

    // 2 dbuf x (A 32K + B 32K) = 128 KB
    __shared__ unsigned short sm[4][BM2 * BK];

    const int tid  = threadIdx.x;
    const int lane = tid & 63;
    const int wave = tid >> 6;
    const int wm   = wave & 1;     // 2 M-halves of 128 rows
    const int wn   = wave >> 1;    // 4 N-quarters of 64 cols
    const int lrow = lane & 15;
    const int quad = lane >> 4;
    const int rdsl = lrow & 7;

    f4 acc[8][4];
#pragma unroll
    for (int i = 0; i < 8; ++i)
#pragma unroll
        for (int j = 0; j < 4; ++j) acc[i][j] = (f4)0.0f;

    const unsigned short* Arow = A  + (long)m0 * lda;
    const unsigned short* Brow = Bt + (long)n0 * ldb;
    const int ktiles = kt1 - kt0;   // >= 4 at every call site

    // 16-fragment set: af[8] (one A-half at a time), bg0/bg1 (B quarters).
    short8 af[8], bg0[4], bg1[4];

    // prologue: stage tiles 0,1; counted drain of tile0 (tile1 in flight);
    // barrier publishes tile0 residency for all waves; read P0 frags.
    stage_mat<4>(Arow, kt0 * BK, sm[0], lda, tid);
    stage_mat<4>(Brow, kt0 * BK, sm[1], ldb, tid);
    stage_mat<4>(Arow, (kt0 + 1) * BK, sm[2], lda, tid);
    stage_mat<4>(Brow, (kt0 + 1) * BK, sm[3], ldb, tid);
    WAITV8();
    SBAR();
    lda_half<0>(af, sm[0], wm, lrow, quad, rdsl);    // af = lo(t0)
    ldb_q<0>(bg0, sm[1], wn, lrow, quad, rdsl);      // bg0 = q0(t0)

    for (int t = 0; t < ktiles; ++t) {
        const int cur = t & 1;
        const unsigned short* Asb = sm[cur * 2];
        const unsigned short* Bsb = sm[cur * 2 + 1];
        const bool s2 = (t + 2 < ktiles);
        const bool rd = (t + 1 < ktiles);

        // P0: MFMA (lo,q0) -> rows0-3 cols0-1; tail-read bg1<-q1(t); SBAR.
        PRIO1(); mfma_cl<0, 0>(acc, af, bg0); PRIO0();
        ldb_q<1>(bg1, Bsb, wn, lrow, quad, rdsl);
        SBAR();

        // P1: MFMA (lo,q1) -> rows0-3 cols2-3; tail-read af<-hi(t); SBAR
        //     (all waves' A-reads of buf[cur] done before A(t+2)-stage).
        PRIO1(); mfma_cl<0, 2>(acc, af, bg1); PRIO0();
        lda_half<1>(af, Asb, wm, lrow, quad, rdsl);
        SBAR();

        // P2: MFMA (hi,q1) -> rows4-7 cols2-3; tail: stage A(t+2) into
        //     buf[cur].A; counted WAITV4 drains t+1 A+B (t+2A stays in
        //     flight); SBAR => t+1 RESIDENT for all waves.
        PRIO1(); mfma_cl<4, 2>(acc, af, bg1); PRIO0();
        if (s2) { stage_mat<4>(Arow, (kt0 + t + 2) * BK, sm[cur * 2], lda, tid);
                  WAITV4(); }
        else    { WAITV0(); }
        SBAR();

        // P3: head: stage B(t+2) into buf[cur].B (bg1-reads separated by
        //     P2-SBAR); MFMA (hi,q0) -> rows4-7 cols0-1; tail-read next
        //     tile's P0 frags from buf[cur^1] (resident since P2-end); SBAR.
        if (s2) stage_mat<4>(Brow, (kt0 + t + 2) * BK, sm[cur * 2 + 1], ldb, tid);
        PRIO1(); mfma_cl<4, 0>(acc, af, bg0); PRIO0();
        if (rd) {
            const unsigned short* An = sm[(cur ^ 1) * 2];
            const unsigned short* Bn = sm[(cur ^ 1) * 2 + 1];
            lda_half<0>(af, An, wm, lrow, quad, rdsl);
            ldb_q<0>(bg0, Bn, wn, lrow, quad, rdsl);
        }
        SBAR();
    }

    // epilogue: C/D layout col=lane&15, row=quad*4+reg (m89/m91)
    const int row0 = m0 + wm * 128 + quad * 4;
    const int col0 = n0 + wn * 64 + lrow;

    float bj[4];
#pragma unroll
    for (int j = 0; j < 4; ++j) bj[j] = bias ? bias[col0 + j * 16] : 0.0f;

    if ((FLAGS & F_VSPL) && n0 >= vsplit) {
        // Vh region: write transposed to C2[b][d][t], packed 4 bf16 (8B) stores
        const int bidx  = m0 >> 11;               // T=2048 rows per batch
        const int tloc0 = (m0 & 2047) + wm * 128 + quad * 4;
#pragma unroll
        for (int j = 0; j < 4; ++j) {
            const int d = col0 + j * 16 - vsplit;
            unsigned short* base = C2 + (long)bidx * sC2 + (long)d * Tv;
#pragma unroll
            for (int i = 0; i < 8; ++i) {
                const int tt = tloc0 + i * 16;
                unsigned long long pk = 0;
#pragma unroll
                for (int r = 0; r < 4; ++r) {
                    float v = acc[i][j][r] * scale + bj[j];
                    pk |= (unsigned long long)f2bf(v) << (16 * r);
                }
                *(unsigned long long*)(base + tt) = pk;
            }
        }
        return;
    }

    float inv[32];
    if (FLAGS & F_RSCL) {
#pragma unroll
        for (int i = 0; i < 8; ++i)
#pragma unroll
            for (int r = 0; r < 4; ++r)
                inv[i * 4 + r] = rowsums[row0 + i * 16 + r];  // pre-inverted
    }

    float rs[32];
    if (FLAGS & F_RSUM) {
#pragma unroll
        for (int k = 0; k < 32; ++k) rs[k] = 0.0f;
    }

    unsigned short* Cb = (unsigned short*)C;
    float*          Cf = ((FLAGS & F_SPLITK) && split) ? (float*)C2 : (float*)C;
    const long cbase = (long)b * sC;

#pragma unroll
    for (int i = 0; i < 8; ++i) {
#pragma unroll
        for (int j = 0; j < 4; ++j) {
            const int col = col0 + j * 16;
#pragma unroll
            for (int r = 0; r < 4; ++r) {
                const int row = row0 + i * 16 + r;
                float v = acc[i][j][r] * scale;
                if (FLAGS & F_EXP) { v = __expf(v); if (col > row) v = 0.0f; }
                if (FLAGS & F_RSUM) rs[i * 4 + r] += v;
                if (FLAGS & F_RSCL) v *= inv[i * 4 + r];
                if (!((FLAGS & F_SPLITK) && split)) v += bj[j];
                const long off = cbase + (long)row * ldc + col;
                if (FLAGS & F_OBF) Cb[off] = f2bf(v);
                else               Cf[off] = v;
            }
        }
    }

    if (FLAGS & F_RSUM) {
        // reduce across the 16 col-lanes (lrow bits), then one atomic per row
#pragma unroll
        for (int k = 0; k < 32; ++k) {
            rs[k] += __shfl_xor(rs[k], 1);
            rs[k] += __shfl_xor(rs[k], 2);
            rs[k] += __shfl_xor(rs[k], 4);
            rs[k] += __shfl_xor(rs[k], 8);
        }
        if (lrow == 0) {
#pragma unroll
            for (int i = 0; i < 8; ++i)
#pragma unroll
                for (int r = 0; r < 4; ++r)
                    atomicAdd(&rowsums[row0 + i * 16 + r], rs[i * 4 + r]);
        }
    }
}

// ---------------------------------------------------------------------------
// 128x256 2-phase core (R9-verified). Used ONLY for step 3b (Vh -> Vt).
// GX,GY as above.
// ---------------------------------------------------------------------------
template<int FLAGS, int GX = 0, int GY = 0>
__global__ __launch_bounds__(512)
void gemmw(const unsigned short* __restrict__ A,
           const unsigned short* __restrict__ Bt,
           void* __restrict__ C,
           const float* __restrict__ bias,
           int M, int N, int K, int lda, int ldb, int ldc,
           long sA, long sB, long sC,
           float scale,
           unsigned short* __restrict__ C2, long sC2, int Tv, int vsplit,
           float* __restrict__ rowsums)
{
    const int b = blockIdx.z;
    A  += (long)b * sA;
    Bt += (long)b * sB;

    int bxr = blockIdx.x, byr = blockIdx.y;
    if (GX > 0) {
        constexpr int NWG = GX * GY;
        constexpr int Q   = NWG >> 3;
        static_assert((NWG & 7) == 0, "swizzle needs NWG%8==0");
        const int lin  = byr * GX + bxr;
        const int virt = (lin & 7) * Q + (lin >> 3);
        bxr = virt % GX; byr = virt / GX;
    }

    const int m0 = byr * BM3;
    const int n0 = bxr * BN3;
    const int kt1 = K / BK;

    // 2 dbuf x (A 16K + B 32K) = 96 KB
    __shared__ unsigned short smA[2][BM3 * BK];
    __shared__ unsigned short smB[2][BN3 * BK];

    const int tid  = threadIdx.x;
    const int lane = tid & 63;
    const int wave = tid >> 6;
    const int wm   = wave & 1;     // 2 M-halves of 64 rows
    const int wn   = wave >> 1;    // 4 N-quarters of 64 cols
    const int lrow = lane & 15;
    const int quad = lane >> 4;
    const int rdsl = lrow & 7;

    f4 acc[4][4];
#pragma unroll
    for (int i = 0; i < 4; ++i)
#pragma unroll
        for (int j = 0; j < 4; ++j) acc[i][j] = (f4)0.0f;

    const unsigned short* Arow = A  + (long)m0 * lda;
    const unsigned short* Brow = Bt + (long)n0 * ldb;
    const int ktiles = kt1;

    short8 af[8], bg0[4], bg1[4];

    stage_mat<2>(Arow, 0, smA[0], lda, tid);
    stage_mat<4>(Brow, 0, smB[0], ldb, tid);
    stage_mat<2>(Arow, BK, smA[1], lda, tid);
    stage_mat<4>(Brow, BK, smB[1], ldb, tid);
    WAITV6();
    SBAR();
    lda_w(af, smA[0], wm, lrow, quad, rdsl);
    ldb_q<0>(bg0, smB[0], wn, lrow, quad, rdsl);

    for (int t = 0; t < ktiles; ++t) {
        const int cur = t & 1;
        const bool s2 = (t + 2 < ktiles);
        const bool rd = (t + 1 < ktiles);

        // P0: MFMA af*bg0 -> cols 0-1; tail-read bg1<-q1(t); SBAR.
        PRIO1(); mfma16<0>(acc, af, bg0); PRIO0();
        ldb_q<1>(bg1, smB[cur], wn, lrow, quad, rdsl);
        SBAR();

        // P1: MFMA af*bg1 -> cols 2-3; tail: stage A(t+2)+B(t+2) into
        //     buf[cur]; WAITV6 drains t+1 (t+2's 6 in flight); SBAR; read
        //     next tile's frags.
        PRIO1(); mfma16<2>(acc, af, bg1); PRIO0();
        if (s2) {
            stage_mat<2>(Arow, (t + 2) * BK, smA[cur], lda, tid);
            stage_mat<4>(Brow, (t + 2) * BK, smB[cur], ldb, tid);
            WAITV6();
        } else {
            WAITV0();
        }
        SBAR();
        if (rd) {
            lda_w(af, smA[cur ^ 1], wm, lrow, quad, rdsl);
            ldb_q<0>(bg0, smB[cur ^ 1], wn, lrow, quad, rdsl);
        }
    }

    // epilogue: C/D layout col=lane&15, row=quad*4+reg (m89/m91)
    const int row0 = m0 + wm * 64 + quad * 4;
    const int col0 = n0 + wn * 64 + lrow;

    float bj[4];
#pragma unroll
    for (int j = 0; j < 4; ++j) bj[j] = bias ? bias[col0 + j * 16] : 0.0f;

    if ((FLAGS & F_VSPL) && n0 >= vsplit) {
        // Vh region: write transposed to C2[b][d][t], packed 4 bf16 (8B) stores
        const int bidx  = m0 >> 11;               // T=2048 rows per batch
        const int tloc0 = (m0 & 2047) + wm * 64 + quad * 4;
#pragma unroll
        for (int j = 0; j < 4; ++j) {
            const int d = col0 + j * 16 - vsplit;
            unsigned short* base = C2 + (long)bidx * sC2 + (long)d * Tv;
#pragma unroll
            for (int i = 0; i < 4; ++i) {
                const int tt = tloc0 + i * 16;
                unsigned long long pk = 0;
#pragma unroll
                for (int r = 0; r < 4; ++r) {
                    float v = acc[i][j][r] * scale + bj[j];
                    pk |= (unsigned long long)f2bf(v) << (16 * r);
                }
                *(unsigned long long*)(base + tt) = pk;
            }
        }
        return;
    }

    unsigned short* Cb = (unsigned short*)C;
    float*          Cf = (float*)C;
    const long cbase = (long)b * sC;

#pragma unroll
    for (int i = 0; i < 4; ++i) {
#pragma unroll
        for (int j = 0; j < 4; ++j) {
            const int col = col0 + j * 16;
#pragma unroll
            for (int r = 0; r < 4; ++r) {
                const int row = row0 + i * 16 + r;
                float v = acc[i][j][r] * scale + bj[j];
                const long off = cbase + (long)row * ldc + col;
                if (FLAGS & F_OBF) Cb[off] = f2bf(v);
                else               Cf[off] = v;
            }
        }
    }
}

// ---------------------------------------------------------------------------
// combine_upper: out[b][1024+..][*] += part[b][1024+..][*]  (float4)
// ---------------------------------------------------------------------------
__global__ void combine_upper(float* __restrict__ out,
                              const float* __restrict__ part)
{
    const long base = ((long)blockIdx.y * 2048 + 1024) * 1024 / 4;  // f4 units
    const long i = base + blockIdx.x * 256 + threadIdx.x;
    f4 a = ((f4*)out)[i];
    f4 bb = ((const f4*)part)[i];
    a.x += bb.x; a.y += bb.y; a.z += bb.z; a.w += bb.w;
    ((f4*)out)[i] = a;
}

// ---------------------------------------------------------------------------
// recip_sums: s[i] = 1/s[i]  (so PV epilogue multiplies instead of divides)
// ---------------------------------------------------------------------------
__global__ void recip_sums(float* __restrict__ s)
{
    const int i = blockIdx.x * 256 + threadIdx.x;
    s[i] = 1.0f / s[i];
}

// ---------------------------------------------------------------------------
// gemv: bhh[m] = dot(Wht[m][:], bv) + bh[m]
// ---------------------------------------------------------------------------
__global__ void gemv_bhh(const unsigned short* __restrict__ Wht,
                         const float* __restrict__ bv,
                         const float* __restrict__ bh,
                         float* __restrict__ bhh)
{
    const int m = blockIdx.x;
    const int tid = threadIdx.x;
    const int lane = tid & 63, wave = tid >> 6;
    __shared__ float red[4];
    const unsigned short* row = Wht + (long)m * 1024;
    float s = 0.0f;
#pragma unroll
    for (int k = 0; k < 4; ++k) {
        const int idx = tid * 4 + k;
        s += bf2f(row[idx]) * bv[idx];
    }
    for (int o = 32; o > 0; o >>= 1) s += __shfl_down(s, o);
    if (lane == 0) red[wave] = s;
    __syncthreads();
    if (tid == 0) bhh[m] = red[0] + red[1] + red[2] + red[3] + bh[m];
}

// ---------------------------------------------------------------------------
// prep: x cast [0,8192) | Wv plain cast [8192,9216) |
//       transposes Wq/Wk/Wh [9216,12288) | biases [12288]
// ---------------------------------------------------------------------------
__global__ void prep(const float* __restrict__ x,
                     const float* __restrict__ Wq, const float* __restrict__ Wk,
                     const float* __restrict__ Wv, const float* __restrict__ Wh,
                     const float* __restrict__ bq, const float* __restrict__ bk,
                     unsigned short* __restrict__ Xbf,
                     unsigned short* __restrict__ Wqkvt,
                     unsigned short* __restrict__ Wht,
                     unsigned short* __restrict__ Wvb,
                     float* __restrict__ bqkv)
{
    __shared__ unsigned short tsh[32][33];
    const int bid = blockIdx.x;
    const int tid = threadIdx.x;

    if (bid < 8192) {                       // cast x
        const int i = bid * 256 + tid;
        f4 v = ((const f4*)x)[i];
        unsigned long long p = (unsigned long long)f2bf(v.x)
                             | ((unsigned long long)f2bf(v.y) << 16)
                             | ((unsigned long long)f2bf(v.z) << 32)
                             | ((unsigned long long)f2bf(v.w) << 48);
        ((unsigned long long*)Xbf)[i] = p;
    } else if (bid < 9216) {                // plain cast Wv
        const int i = (bid - 8192) * 256 + tid;
        f4 v = ((const f4*)Wv)[i];
        unsigned long long p = (unsigned long long)f2bf(v.x)
                             | ((unsigned long long)f2bf(v.y) << 16)
                             | ((unsigned long long)f2bf(v.z) << 32)
                             | ((unsigned long long)f2bf(v.w) << 48);
        ((unsigned long long*)Wvb)[i] = p;
    } else if (bid < 12288) {               // transpose+cast Wq, Wk, Wh
        const int wi = bid - 9216;
        const int w = wi >> 10, tile = wi & 1023;
        const float* src = (w == 0) ? Wq : (w == 1) ? Wk : Wh;
        unsigned short* dst = (w == 0) ? Wqkvt : (w == 1) ? (Wqkvt + 1024 * 1024) : Wht;
        const int c0 = (tile & 31) * 32, r0 = (tile >> 5) * 32;
        const int xx = tid & 31, yy = tid >> 5;
        for (int i = yy; i < 32; i += 8)
            tsh[i][xx] = f2bf(src[(long)(r0 + i) * 1024 + c0 + xx]);
        __syncthreads();
        for (int i = yy; i < 32; i += 8)
            dst[(long)(c0 + i) * 1024 + r0 + xx] = tsh[xx][i];
    } else {                                // biases: Q, K real; Vh third = 0
        const int i = (bid - 12288) * 256 + tid;
        if (i < 1024) { bqkv[i] = bq[i]; bqkv[1024 + i] = bk[i]; bqkv[2048 + i] = 0.0f; }
    }
}

// ---------------------------------------------------------------------------
extern "C" void kernel_launch(void* const* d_in, const int* in_sizes, int n_in,
                              void* d_out, int out_size, void* d_ws, size_t ws_size,
                              hipStream_t stream)
{
    const float* x  = (const float*)d_in[0];
    const float* Wq = (const float*)d_in[1];
    const float* bq = (const float*)d_in[2];
    const float* Wk = (const float*)d_in[3];
    const float* bk = (const float*)d_in[4];
    const float* Wv = (const float*)d_in[5];
    const float* bv = (const float*)d_in[6];
    const float* Wh = (const float*)d_in[7];
    const float* bh = (const float*)d_in[8];
    float* out = (float*)d_out;

    const int  Bb = 4, T = 2048, Dm = 1024;
    const long BT = (long)Bb * T;

    unsigned short* ws = (unsigned short*)d_ws;
    size_t o = 0;
    unsigned short* Xbf   = ws + o; o += (size_t)BT * Dm;         // 16 MB
    unsigned short* Wqkvt = ws + o; o += (size_t)3 * Dm * Dm;     //  6 MB (3rd = Wvh^T)
    unsigned short* Wht   = ws + o; o += (size_t)Dm * Dm;         //  2 MB
    unsigned short* Wvb   = ws + o; o += (size_t)Dm * Dm;         //  2 MB
    float* bqkv = (float*)(ws + o); o += (size_t)3 * Dm * 2;      // 12 KB
    float* bhh  = (float*)(ws + o); o += (size_t)Dm * 2;          //  4 KB
    float* sums = (float*)(ws + o); o += (size_t)BT * 2;          // 32 KB
    unsigned short* QKV   = ws + o; o += (size_t)BT * 3 * Dm;     // 48 MB
    unsigned short* Vt    = ws + o; o += (size_t)BT * Dm;         // 16 MB (Vh^T)
    unsigned short* Pp    = ws + o; o += (size_t)Bb * T * T;      // 32 MB (P' = exp(s))
    float* part = (float*)(ws + o);                               // 32 MB fp32 partial

    const dim3 blk(256);
    const dim3 blk2(512);
    const long sRow3 = (long)T * 3 * Dm;

    // 0. zero row-sum accumulators (32 KB)
    hipMemsetAsync(sums, 0, (size_t)BT * sizeof(float), stream);

    // 1. prep: casts, transposes, biases
    prep<<<12289, blk, 0, stream>>>(x, Wq, Wk, Wv, Wh, bq, bk,
                                    Xbf, Wqkvt, Wht, Wvb, bqkv);

    // 2a. Wvh^T = (Wv@Wh)^T : C[m][n] = sum_k Wht[m][k]*Wvb[n][k] -> bf16
    gemm_bt<F_OBF><<<dim3(Dm / BN, Dm / BM, 1), blk, 0, stream>>>(
        Wht, Wvb, Wqkvt + 2 * Dm * Dm, nullptr, Dm, Dm, Dm, Dm, Dm, Dm,
        0, 0, 0, 1.0f, nullptr, 0, 0, 0, nullptr);

    // 2b. bhh = bv@Wh + bh
    gemv_bhh<<<Dm, blk, 0, stream>>>(Wht, bv, bh, bhh);

    // 3a. Q,K projection: 256^2 core; grid (8,32) = 256 blocks = EXACTLY
    //     1.0 round. Writes cols [0,2048) of QKV (ldc=3072). <8,32> swizzle.
    gemm256<F_OBF, 8, 32>
        <<<dim3(2 * Dm / BN2, BT / BM2, 1), blk2, 0, stream>>>(
        Xbf, Wqkvt, QKV, bqkv, (int)BT, 2 * Dm, Dm, Dm, Dm, 3 * Dm,
        0, 0, 0, 1.0f, nullptr, 0, 0, 0, nullptr);

    // 3b. Vh = x@(Wv@Wh) written TRANSPOSED into Vt: 128x256 core; grid
    //     (4,64) = 256 blocks = EXACTLY 1.0 round. vsplit=0 -> all blocks
    //     take the Vt path (QKV cols [2048,3072) never written/read).
    //     Vh bias is zero -> bias=nullptr. <4,64> swizzle.
    gemmw<F_OBF | F_VSPL, 4, 64>
        <<<dim3(Dm / BN3, BT / BM3, 1), blk2, 0, stream>>>(
        Xbf, Wqkvt + 2 * Dm * Dm, QKV, nullptr, (int)BT, Dm, Dm, Dm, Dm, 3 * Dm,
        0, 0, 0, 1.0f, Vt, (long)Dm * T, T, 0, nullptr);

    // 4. P' = exp(Q@K^T / 32) * mask -> bf16 + atomic row-sums, tile-skip,
    //    rev-y. grid (8, 8, Bb) == <GX=8, GY=8> swizzle.
    gemm256<F_OBF | F_SKIP | F_REVY | F_EXP | F_RSUM, 8, 8>
        <<<dim3(T / BN2, T / BM2, Bb), blk2, 0, stream>>>(
        QKV, QKV + Dm, Pp, nullptr, T, T, Dm, 3 * Dm, 3 * Dm, T,
        sRow3, sRow3, (long)T * T, 1.0f / 32.0f,
        nullptr, 0, 0, 0, sums);

    // 4b. invert row sums once (PV epilogue multiplies)
    recip_sums<<<dim3((int)(BT / 256)), blk, 0, stream>>>(sums);

    // 5. out = (P' @ Vh^T) * rsum[row] + bhh, split-K2 (split1 -> part)
    //    grid (8, 8, Bb) == <GX=8, GY=8> SALU XCD swizzle
    gemm256<F_KLIM | F_REVY | F_RSCL | F_SPLITK, 8, 8>
        <<<dim3(2 * Dm / BN2, T / BM2, Bb), blk2, 0, stream>>>(
        Pp, Vt, out, bhh, T, Dm, T, T, T, Dm,
        (long)T * T, (long)Dm * T, (long)T * Dm, 1.0f,
        (unsigned short*)part, 0, 0, 0, sums);

    // 6. out upper rows += part upper rows
    combine_upper<<<dim3(1024, Bb), blk, 0, stream>>>(out, part);
}

// Round 11
// 270.354 us; speedup vs baseline: 1.1639x; 1.0157x over previous
//
#include <hip/hip_runtime.h>

// B=4, T=2048, D=1024, fp32 in/out, bf16-tolerance threshold.
// Algebra: out = softmax(QK^T/32)@V@Wh + bh = P_norm@(x@(Wv@Wh)) + (bv@Wh + bh).
// Pipeline: prep(+sums zero) -> Wvh^T small GEMM (128^2) -> gemv bhh ->
//   3a Q,K projection (256^2, 256 blocks = 1.0 round) ->
//   3b Vh -> Vt transposed (128x256, 256 blocks = 1.0 round) ->
//   4 scores TRANSPOSED (256^2 + F_TRS: S^T = K@Q^T -> packed 8B stores into
//     Pp[t][s], per-col rowsums) -> 5 PV split-K2 (256^2; epilogue computes
//     1/rowsum inline) -> combine_upper.
//
// R11 = R10 (best, 274.6us) + launch folding (memset+recip -> gone) +
//   step-4 operand swap (F_TRS): C/D layout has 4 consecutive ROWS per reg
//   quad -> computing S^T makes "rows"=s -> 4xbf16 packed 8B stores into
//   Pp[t][s] (vs 128 scalar 2B), and rowsums become per-col: 2 shuffles
//   (xor16/32) + 4 atomics/lane-quad vs 4x32 shuffles. Mask: row>col.
//   Skip: m0 > n0+255 (36 active tiles/batch, unchanged count).
//
// 256^2 core (R6-verified, DO NOT TOUCH): 2 waves/SIMD -> HARD 256 regs/wave;
//   acc[8][4]=128 AGPR + 16 short8 frags. 4 phases/K-tile, ONE barrier each
//   (ladder: 8/4/2 barriers = 81/70.5/82us -> 4 optimal). One-phase-ahead
//   reads; counted vmcnt (WAITV4 at P2, never 0 in steady state).
// 128x256 core (R9-verified): 2 phases/K-tile, 96KB LDS, WAITV6.
// XCD swizzle (T1): SALU-only, compile-time GX,GY == ACTUAL grid dims
//   (R5 bug: mismatch -> non-bijective -> wrong results).

typedef __attribute__((ext_vector_type(8)))  short short8;     // MFMA A/B frag
typedef __attribute__((ext_vector_type(4)))  float f4;         // MFMA 16x16 C/D

#define BM 128
#define BN 128
#define BK 64
#define BM2 256
#define BN2 256
#define BM3 128
#define BN3 256

// flag bits
#define F_OBF    1     // out bf16
#define F_SKIP   2     // causal tile-skip
#define F_KLIM   4     // causal K-limit
#define F_REVY   8     // reverse-y dispatch
#define F_VSPL   16    // V-split transposed write (n0>=vsplit -> C2)
#define F_RSCL   32    // epilogue * 1/rowsums[row] (divide inline)
#define F_EXP    64    // exp + causal-mask epilogue
#define F_RSUM   128   // atomic row-sum accumulate (with F_EXP)
#define F_SPLITK 256   // split-K2 at k=1024 (PV); split1 -> C2 fp32 partial
#define F_TRS    512   // transposed-scores mode (S^T): packed stores, col-sums

#define WAITV4() asm volatile("s_waitcnt vmcnt(4)" ::: "memory")
#define WAITV6() asm volatile("s_waitcnt vmcnt(6)" ::: "memory")
#define WAITV8() asm volatile("s_waitcnt vmcnt(8)" ::: "memory")
#define WAITV0() asm volatile("s_waitcnt vmcnt(0)" ::: "memory")
#define SBAR()   __builtin_amdgcn_s_barrier()
#define PRIO1()  __builtin_amdgcn_s_setprio(1)
#define PRIO0()  __builtin_amdgcn_s_setprio(0)

__device__ inline unsigned short f2bf(float f) {
    union { float f; unsigned u; } c; c.f = f;
    unsigned u = c.u;
    return (unsigned short)((u + 0x7fffu + ((u >> 16) & 1u)) >> 16);  // RNE
}
__device__ inline float bf2f(unsigned short u) {
    union { unsigned u; float f; } c; c.u = ((unsigned)u) << 16;
    return c.f;
}
__device__ inline void gload16(const void* g, void* l) {
    __builtin_amdgcn_global_load_lds(
        (const __attribute__((address_space(1))) void*)g,
        (__attribute__((address_space(3))) void*)l,
        16, 0, 0);
}

// ---------------------------------------------------------------------------
// OLD 128x128 core (kept for the small Wvh^T GEMM only).
// ---------------------------------------------------------------------------
template<int FLAGS>
__global__ __launch_bounds__(256)
void gemm_bt(const unsigned short* __restrict__ A,
             const unsigned short* __restrict__ Bt,
             void* __restrict__ C,
             const float* __restrict__ bias,
             int M, int N, int K, int lda, int ldb, int ldc,
             long sA, long sB, long sC,
             float scale,
             unsigned short* __restrict__ C2, long sC2, int Tv, int vsplit,
             float* __restrict__ rowsums)
{
    const int b = blockIdx.z;
    A  += (long)b * sA;
    Bt += (long)b * sB;

    int by = blockIdx.y;
    if (FLAGS & F_REVY) by = gridDim.y - 1 - by;
    const int m0 = by * BM;
    const int n0 = blockIdx.x * BN;

    const int kt1 = K / BK;

    __shared__ unsigned short As[BM * BK];   // 16 KB
    __shared__ unsigned short Bs[BN * BK];   // 16 KB

    const int tid  = threadIdx.x;
    const int lane = tid & 63;
    const int wave = tid >> 6;
    const int wm   = wave & 1;
    const int wn   = wave >> 1;
    const int lrow = lane & 15;
    const int quad = lane >> 4;

    f4 acc[4][4];
#pragma unroll
    for (int i = 0; i < 4; ++i)
#pragma unroll
        for (int j = 0; j < 4; ++j) acc[i][j] = (f4)0.0f;

    const int srow = tid >> 3;
    const int gco  = ((tid & 7) ^ (srow & 7)) << 3;
    const int rdsl = (lrow & 7);

    for (int kt = 0; kt < kt1; ++kt) {
        const int k0 = kt * BK;
#pragma unroll
        for (int d = 0; d < 4; ++d) {
            const int row = d * 32 + srow;
            const unsigned short* ga = A  + (long)(m0 + row) * lda + k0 + gco;
            const unsigned short* gb = Bt + (long)(n0 + row) * ldb + k0 + gco;
            const int ldsoff = (d * 256 + wave * 64) * 16;
            gload16(ga, (char*)As + ldsoff);
            gload16(gb, (char*)Bs + ldsoff);
        }
        __syncthreads();

#pragma unroll
        for (int ks = 0; ks < 2; ++ks) {
            const int slot = ((ks * 4 + quad) ^ rdsl) << 3;
            short8 af[4], bfr[4];
#pragma unroll
            for (int i = 0; i < 4; ++i) {
                af[i]  = *(const short8*)(As + (wm * 64 + i * 16 + lrow) * BK + slot);
                bfr[i] = *(const short8*)(Bs + (wn * 64 + i * 16 + lrow) * BK + slot);
            }
#pragma unroll
            for (int i = 0; i < 4; ++i)
#pragma unroll
                for (int j = 0; j < 4; ++j)
                    acc[i][j] = __builtin_amdgcn_mfma_f32_16x16x32_bf16(
                        af[i], bfr[j], acc[i][j], 0, 0, 0);
        }
        __syncthreads();
    }

    const int row0 = m0 + wm * 64 + quad * 4;
    const int col0 = n0 + wn * 64 + lrow;

    float bj[4];
#pragma unroll
    for (int j = 0; j < 4; ++j) bj[j] = bias ? bias[col0 + j * 16] : 0.0f;

    unsigned short* Cb = (unsigned short*)C;
    float*          Cf = (float*)C;
    const long cbase = (long)b * sC;

#pragma unroll
    for (int i = 0; i < 4; ++i) {
#pragma unroll
        for (int j = 0; j < 4; ++j) {
            const int col = col0 + j * 16;
#pragma unroll
            for (int r = 0; r < 4; ++r) {
                const int row = row0 + i * 16 + r;
                float v = acc[i][j][r] * scale + bj[j];
                const long off = cbase + (long)row * ldc + col;
                if (FLAGS & F_OBF) Cb[off] = f2bf(v);
                else               Cf[off] = v;
            }
        }
    }
}

// ---------------------------------------------------------------------------
// shared helpers for the 512-thread cores
// ---------------------------------------------------------------------------
template<int QB>
__device__ inline void ldb_q(short8 (&bq)[4], const unsigned short* Bsb,
                             int wn, int lrow, int quad, int rdsl)
{
#pragma unroll
    for (int j = 0; j < 2; ++j)
#pragma unroll
        for (int ks = 0; ks < 2; ++ks)
            bq[j * 2 + ks] = *(const short8*)(
                Bsb + (wn * 64 + QB * 32 + j * 16 + lrow) * BK
                    + (((ks * 4 + quad) ^ rdsl) << 3));
}

template<int ND>
__device__ inline void stage_mat(const unsigned short* __restrict__ Row,
                                 int k0, unsigned short* Ls, int ld, int tid)
{
    const int srow = tid >> 3;                       // row = d*64 + srow
    const int gco  = ((tid & 7) ^ (srow & 7)) << 3;  // pre-swizzled global chunk
    const int wave = tid >> 6;
#pragma unroll
    for (int d = 0; d < ND; ++d) {
        const int row = d * 64 + srow;
        const int ldsoff = (d * 512 + wave * 64) * 16;   // bytes, wave-uniform
        gload16(Row + (long)row * ld + k0 + gco, (char*)Ls + ldsoff);
    }
}

// --- 256^2 core helpers ---
template<int HA>
__device__ inline void lda_half(short8 (&af)[8], const unsigned short* Asb,
                                int wm, int lrow, int quad, int rdsl)
{
#pragma unroll
    for (int i = 0; i < 4; ++i)
#pragma unroll
        for (int ks = 0; ks < 2; ++ks)
            af[i * 2 + ks] = *(const short8*)(
                Asb + (wm * 128 + HA * 64 + i * 16 + lrow) * BK
                    + (((ks * 4 + quad) ^ rdsl) << 3));
}

template<int RI, int CJ>
__device__ inline void mfma_cl(f4 (&acc)[8][4], const short8 (&a)[8],
                               const short8 (&b)[4])
{
#pragma unroll
    for (int ks = 0; ks < 2; ++ks)
#pragma unroll
        for (int i = 0; i < 4; ++i)
#pragma unroll
            for (int j = 0; j < 2; ++j)
                acc[RI + i][CJ + j] = __builtin_amdgcn_mfma_f32_16x16x32_bf16(
                    a[i * 2 + ks], b[j * 2 + ks], acc[RI + i][CJ + j], 0, 0, 0);
}

// --- 128x256 core helpers ---
__device__ inline void lda_w(short8 (&af)[8], const unsigned short* Asb,
                             int wm, int lrow, int quad, int rdsl)
{
#pragma unroll
    for (int i = 0; i < 4; ++i)
#pragma unroll
        for (int ks = 0; ks < 2; ++ks)
            af[i * 2 + ks] = *(const short8*)(
                Asb + (wm * 64 + i * 16 + lrow) * BK
                    + (((ks * 4 + quad) ^ rdsl) << 3));
}

template<int CJ>
__device__ inline void mfma16(f4 (&acc)[4][4], const short8 (&a)[8],
                              const short8 (&b)[4])
{
#pragma unroll
    for (int ks = 0; ks < 2; ++ks)
#pragma unroll
        for (int i = 0; i < 4; ++i)
#pragma unroll
            for (int j = 0; j < 2; ++j)
                acc[i][CJ + j] = __builtin_amdgcn_mfma_f32_16x16x32_bf16(
                    a[i * 2 + ks], b[j * 2 + ks], acc[i][CJ + j], 0, 0, 0);
}

// ---------------------------------------------------------------------------
// C = A[M,K] @ Bt[N,K]^T, bf16 in, fp32/bf16 out. 256^2 4-phase core.
// GX,GY MUST equal the launch grid dims (bijectivity!).
// ---------------------------------------------------------------------------
template<int FLAGS, int GX = 0, int GY = 0>
__global__ __launch_bounds__(512)
void gemm256(const unsigned short* __restrict__ A,
             const unsigned short* __restrict__ Bt,
             void* __restrict__ C,
             const float* __restrict__ bias,
             int M, int N, int K, int lda, int ldb, int ldc,
             long sA, long sB, long sC,
             float scale,
             unsigned short* __restrict__ C2, long sC2, int Tv, int vsplit,
             float* __restrict__ rowsums)
{
    const int b = blockIdx.z;
    A  += (long)b * sA;
    Bt += (long)b * sB;
    if (FLAGS & (F_RSCL | F_RSUM)) rowsums += (long)b * M;

    int bxr = blockIdx.x, byr = blockIdx.y;
    if (GX > 0) {
        constexpr int NWG = GX * GY;
        constexpr int Q   = NWG >> 3;
        static_assert((NWG & 7) == 0, "swizzle needs NWG%8==0");
        const int lin  = byr * GX + bxr;
        const int virt = (lin & 7) * Q + (lin >> 3);
        bxr = virt % GX; byr = virt / GX;
    }

    int by = byr;
    if (FLAGS & F_REVY) by = gridDim.y - 1 - by;
    const int m0 = by * BM2;

    int n0, split = 0;
    if (FLAGS & F_SPLITK) {
        const int nbx = N / BN2;
        n0 = (bxr % nbx) * BN2;
        split = bxr / nbx;
        if (split && m0 < 1024) return;
    } else {
        n0 = bxr * BN2;
    }

    if (FLAGS & F_SKIP) {
        if (FLAGS & F_TRS) { if (m0 > n0 + (BM2 - 1)) return; }  // masked: s>t
        else               { if (n0 > m0 + (BM2 - 1)) return; }
    }

    int kend = K;
    if (FLAGS & F_KLIM) { int ke = m0 + BM2; kend = ke < K ? ke : K; }
    int kt0 = 0;
    if (FLAGS & F_SPLITK) {
        if (split == 0) { if (kend > 1024) kend = 1024; }
        else            { kt0 = 1024 / BK; }
    }
    const int kt1 = kend / BK;

    // 2 dbuf x (A 32K + B 32K) = 128 KB
    __shared__ unsigned short sm[4][BM2 * BK];

    const int tid  = threadIdx.x;
    const int lane = tid & 63;
    const int wave = tid >> 6;
    const int wm   = wave & 1;     // 2 M-halves of 128 rows
    const int wn   = wave >> 1;    // 4 N-quarters of 64 cols
    const int lrow = lane & 15;
    const int quad = lane >> 4;
    const int rdsl = lrow & 7;

    f4 acc[8][4];
#pragma unroll
    for (int i = 0; i < 8; ++i)
#pragma unroll
        for (int j = 0; j < 4; ++j) acc[i][j] = (f4)0.0f;

    const unsigned short* Arow = A  + (long)m0 * lda;
    const unsigned short* Brow = Bt + (long)n0 * ldb;
    const int ktiles = kt1 - kt0;   // >= 4 at every call site

    // 16-fragment set: af[8] (one A-half at a time), bg0/bg1 (B quarters).
    short8 af[8], bg0[4], bg1[4];

    // prologue: stage tiles 0,1; counted drain of tile0 (tile1 in flight);
    // barrier publishes tile0 residency for all waves; read P0 frags.
    stage_mat<4>(Arow, kt0 * BK, sm[0], lda, tid);
    stage_mat<4>(Brow, kt0 * BK, sm[1], ldb, tid);
    stage_mat<4>(Arow, (kt0 + 1) * BK, sm[2], lda, tid);
    stage_mat<4>(Brow, (kt0 + 1) * BK, sm[3], ldb, tid);
    WAITV8();
    SBAR();
    lda_half<0>(af, sm[0], wm, lrow, quad, rdsl);    // af = lo(t0)
    ldb_q<0>(bg0, sm[1], wn, lrow, quad, rdsl);      // bg0 = q0(t0)

    for (int t = 0; t < ktiles; ++t) {
        const int cur = t & 1;
        const unsigned short* Asb = sm[cur * 2];
        const unsigned short* Bsb = sm[cur * 2 + 1];
        const bool s2 = (t + 2 < ktiles);
        const bool rd = (t + 1 < ktiles);

        // P0: MFMA (lo,q0) -> rows0-3 cols0-1; tail-read bg1<-q1(t); SBAR.
        PRIO1(); mfma_cl<0, 0>(acc, af, bg0); PRIO0();
        ldb_q<1>(bg1, Bsb, wn, lrow, quad, rdsl);
        SBAR();

        // P1: MFMA (lo,q1) -> rows0-3 cols2-3; tail-read af<-hi(t); SBAR
        //     (all waves' A-reads of buf[cur] done before A(t+2)-stage).
        PRIO1(); mfma_cl<0, 2>(acc, af, bg1); PRIO0();
        lda_half<1>(af, Asb, wm, lrow, quad, rdsl);
        SBAR();

        // P2: MFMA (hi,q1) -> rows4-7 cols2-3; tail: stage A(t+2) into
        //     buf[cur].A; counted WAITV4 drains t+1 A+B (t+2A stays in
        //     flight); SBAR => t+1 RESIDENT for all waves.
        PRIO1(); mfma_cl<4, 2>(acc, af, bg1); PRIO0();
        if (s2) { stage_mat<4>(Arow, (kt0 + t + 2) * BK, sm[cur * 2], lda, tid);
                  WAITV4(); }
        else    { WAITV0(); }
        SBAR();

        // P3: head: stage B(t+2) into buf[cur].B (bg1-reads separated by
        //     P2-SBAR); MFMA (hi,q0) -> rows4-7 cols0-1; tail-read next
        //     tile's P0 frags from buf[cur^1] (resident since P2-end); SBAR.
        if (s2) stage_mat<4>(Brow, (kt0 + t + 2) * BK, sm[cur * 2 + 1], ldb, tid);
        PRIO1(); mfma_cl<4, 0>(acc, af, bg0); PRIO0();
        if (rd) {
            const unsigned short* An = sm[(cur ^ 1) * 2];
            const unsigned short* Bn = sm[(cur ^ 1) * 2 + 1];
            lda_half<0>(af, An, wm, lrow, quad, rdsl);
            ldb_q<0>(bg0, Bn, wn, lrow, quad, rdsl);
        }
        SBAR();
    }

    // epilogue: C/D layout col=lane&15, row=quad*4+reg (m89/m91)
    const int row0 = m0 + wm * 128 + quad * 4;
    const int col0 = n0 + wn * 64 + lrow;

    unsigned short* Cb = (unsigned short*)C;
    const long cbase = (long)b * sC;

    if (FLAGS & F_TRS) {
        // transposed scores: row=s, col=t. exp + mask(s>t), packed 4xbf16
        // (8B) stores into Pp[t][s] (4 consecutive s per reg quad), per-col
        // rowsums via quad shuffles (xor16/32) + 1 atomic per (quad0,j).
        float rsj[4];
#pragma unroll
        for (int j = 0; j < 4; ++j) rsj[j] = 0.0f;
#pragma unroll
        for (int j = 0; j < 4; ++j) {
            const int col = col0 + j * 16;
#pragma unroll
            for (int i = 0; i < 8; ++i) {
                unsigned long long pk = 0;
#pragma unroll
                for (int r = 0; r < 4; ++r) {
                    const int row = row0 + i * 16 + r;
                    float v = __expf(acc[i][j][r] * scale);
                    if (row > col) v = 0.0f;
                    rsj[j] += v;
                    pk |= (unsigned long long)f2bf(v) << (16 * r);
                }
                *(unsigned long long*)(Cb + cbase + (long)col * ldc
                                       + row0 + i * 16) = pk;
            }
        }
#pragma unroll
        for (int j = 0; j < 4; ++j) {
            rsj[j] += __shfl_xor(rsj[j], 16);
            rsj[j] += __shfl_xor(rsj[j], 32);
        }
        if (quad == 0) {
#pragma unroll
            for (int j = 0; j < 4; ++j)
                atomicAdd(&rowsums[col0 + j * 16], rsj[j]);
        }
        return;
    }

    float bj[4];
#pragma unroll
    for (int j = 0; j < 4; ++j) bj[j] = bias ? bias[col0 + j * 16] : 0.0f;

    if ((FLAGS & F_VSPL) && n0 >= vsplit) {
        // Vh region: write transposed to C2[b][d][t], packed 4 bf16 (8B) stores
        const int bidx  = m0 >> 11;               // T=2048 rows per batch
        const int tloc0 = (m0 & 2047) + wm * 128 + quad * 4;
#pragma unroll
        for (int j = 0; j < 4; ++j) {
            const int d = col0 + j * 16 - vsplit;
            unsigned short* base = C2 + (long)bidx * sC2 + (long)d * Tv;
#pragma unroll
            for (int i = 0; i < 8; ++i) {
                const int tt = tloc0 + i * 16;
                unsigned long long pk = 0;
#pragma unroll
                for (int r = 0; r < 4; ++r) {
                    float v = acc[i][j][r] * scale + bj[j];
                    pk |= (unsigned long long)f2bf(v) << (16 * r);
                }
                *(unsigned long long*)(base + tt) = pk;
            }
        }
        return;
    }

    float inv[32];
    if (FLAGS & F_RSCL) {
#pragma unroll
        for (int i = 0; i < 8; ++i)
#pragma unroll
            for (int r = 0; r < 4; ++r)
                inv[i * 4 + r] = 1.0f / rowsums[row0 + i * 16 + r];
    }

    float*          Cf = ((FLAGS & F_SPLITK) && split) ? (float*)C2 : (float*)C;

#pragma unroll
    for (int i = 0; i < 8; ++i) {
#pragma unroll
        for (int j = 0; j < 4; ++j) {
            const int col = col0 + j * 16;
#pragma unroll
            for (int r = 0; r < 4; ++r) {
                const int row = row0 + i * 16 + r;
                float v = acc[i][j][r] * scale;
                if (FLAGS & F_RSCL) v *= inv[i * 4 + r];
                if (!((FLAGS & F_SPLITK) && split)) v += bj[j];
                const long off = cbase + (long)row * ldc + col;
                if (FLAGS & F_OBF) Cb[off] = f2bf(v);
                else               Cf[off] = v;
            }
        }
    }
}

// ---------------------------------------------------------------------------
// 128x256 2-phase core (R9-verified). Used ONLY for step 3b (Vh -> Vt).
// ---------------------------------------------------------------------------
template<int FLAGS, int GX = 0, int GY = 0>
__global__ __launch_bounds__(512)
void gemmw(const unsigned short* __restrict__ A,
           const unsigned short* __restrict__ Bt,
           void* __restrict__ C,
           const float* __restrict__ bias,
           int M, int N, int K, int lda, int ldb, int ldc,
           long sA, long sB, long sC,
           float scale,
           unsigned short* __restrict__ C2, long sC2, int Tv, int vsplit,
           float* __restrict__ rowsums)
{
    const int b = blockIdx.z;
    A  += (long)b * sA;
    Bt += (long)b * sB;

    int bxr = blockIdx.x, byr = blockIdx.y;
    if (GX > 0) {
        constexpr int NWG = GX * GY;
        constexpr int Q   = NWG >> 3;
        static_assert((NWG & 7) == 0, "swizzle needs NWG%8==0");
        const int lin  = byr * GX + bxr;
        const int virt = (lin & 7) * Q + (lin >> 3);
        bxr = virt % GX; byr = virt / GX;
    }

    const int m0 = byr * BM3;
    const int n0 = bxr * BN3;
    const int kt1 = K / BK;

    // 2 dbuf x (A 16K + B 32K) = 96 KB
    __shared__ unsigned short smA[2][BM3 * BK];
    __shared__ unsigned short smB[2][BN3 * BK];

    const int tid  = threadIdx.x;
    const int lane = tid & 63;
    const int wave = tid >> 6;
    const int wm   = wave & 1;     // 2 M-halves of 64 rows
    const int wn   = wave >> 1;    // 4 N-quarters of 64 cols
    const int lrow = lane & 15;
    const int quad = lane >> 4;
    const int rdsl = lrow & 7;

    f4 acc[4][4];
#pragma unroll
    for (int i = 0; i < 4; ++i)
#pragma unroll
        for (int j = 0; j < 4; ++j) acc[i][j] = (f4)0.0f;

    const unsigned short* Arow = A  + (long)m0 * lda;
    const unsigned short* Brow = Bt + (long)n0 * ldb;
    const int ktiles = kt1;

    short8 af[8], bg0[4], bg1[4];

    stage_mat<2>(Arow, 0, smA[0], lda, tid);
    stage_mat<4>(Brow, 0, smB[0], ldb, tid);
    stage_mat<2>(Arow, BK, smA[1], lda, tid);
    stage_mat<4>(Brow, BK, smB[1], ldb, tid);
    WAITV6();
    SBAR();
    lda_w(af, smA[0], wm, lrow, quad, rdsl);
    ldb_q<0>(bg0, smB[0], wn, lrow, quad, rdsl);

    for (int t = 0; t < ktiles; ++t) {
        const int cur = t & 1;
        const bool s2 = (t + 2 < ktiles);
        const bool rd = (t + 1 < ktiles);

        // P0: MFMA af*bg0 -> cols 0-1; tail-read bg1<-q1(t); SBAR.
        PRIO1(); mfma16<0>(acc, af, bg0); PRIO0();
        ldb_q<1>(bg1, smB[cur], wn, lrow, quad, rdsl);
        SBAR();

        // P1: MFMA af*bg1 -> cols 2-3; tail: stage A(t+2)+B(t+2) into
        //     buf[cur]; WAITV6 drains t+1 (t+2's 6 in flight); SBAR; read
        //     next tile's frags.
        PRIO1(); mfma16<2>(acc, af, bg1); PRIO0();
        if (s2) {
            stage_mat<2>(Arow, (t + 2) * BK, smA[cur], lda, tid);
            stage_mat<4>(Brow, (t + 2) * BK, smB[cur], ldb, tid);
            WAITV6();
        } else {
            WAITV0();
        }
        SBAR();
        if (rd) {
            lda_w(af, smA[cur ^ 1], wm, lrow, quad, rdsl);
            ldb_q<0>(bg0, smB[cur ^ 1], wn, lrow, quad, rdsl);
        }
    }

    // epilogue: C/D layout col=lane&15, row=quad*4+reg (m89/m91)
    const int row0 = m0 + wm * 64 + quad * 4;
    const int col0 = n0 + wn * 64 + lrow;

    float bj[4];
#pragma unroll
    for (int j = 0; j < 4; ++j) bj[j] = bias ? bias[col0 + j * 16] : 0.0f;

    if ((FLAGS & F_VSPL) && n0 >= vsplit) {
        // Vh region: write transposed to C2[b][d][t], packed 4 bf16 (8B) stores
        const int bidx  = m0 >> 11;               // T=2048 rows per batch
        const int tloc0 = (m0 & 2047) + wm * 64 + quad * 4;
#pragma unroll
        for (int j = 0; j < 4; ++j) {
            const int d = col0 + j * 16 - vsplit;
            unsigned short* base = C2 + (long)bidx * sC2 + (long)d * Tv;
#pragma unroll
            for (int i = 0; i < 4; ++i) {
                const int tt = tloc0 + i * 16;
                unsigned long long pk = 0;
#pragma unroll
                for (int r = 0; r < 4; ++r) {
                    float v = acc[i][j][r] * scale + bj[j];
                    pk |= (unsigned long long)f2bf(v) << (16 * r);
                }
                *(unsigned long long*)(base + tt) = pk;
            }
        }
        return;
    }

    unsigned short* Cb = (unsigned short*)C;
    float*          Cf = (float*)C;
    const long cbase = (long)b * sC;

#pragma unroll
    for (int i = 0; i < 4; ++i) {
#pragma unroll
        for (int j = 0; j < 4; ++j) {
            const int col = col0 + j * 16;
#pragma unroll
            for (int r = 0; r < 4; ++r) {
                const int row = row0 + i * 16 + r;
                float v = acc[i][j][r] * scale + bj[j];
                const long off = cbase + (long)row * ldc + col;
                if (FLAGS & F_OBF) Cb[off] = f2bf(v);
                else               Cf[off] = v;
            }
        }
    }
}

// ---------------------------------------------------------------------------
// combine_upper: out[b][1024+..][*] += part[b][1024+..][*]  (float4)
// ---------------------------------------------------------------------------
__global__ void combine_upper(float* __restrict__ out,
                              const float* __restrict__ part)
{
    const long base = ((long)blockIdx.y * 2048 + 1024) * 1024 / 4;  // f4 units
    const long i = base + blockIdx.x * 256 + threadIdx.x;
    f4 a = ((f4*)out)[i];
    f4 bb = ((const f4*)part)[i];
    a.x += bb.x; a.y += bb.y; a.z += bb.z; a.w += bb.w;
    ((f4*)out)[i] = a;
}

// ---------------------------------------------------------------------------
// gemv: bhh[m] = dot(Wht[m][:], bv) + bh[m]
// ---------------------------------------------------------------------------
__global__ void gemv_bhh(const unsigned short* __restrict__ Wht,
                         const float* __restrict__ bv,
                         const float* __restrict__ bh,
                         float* __restrict__ bhh)
{
    const int m = blockIdx.x;
    const int tid = threadIdx.x;
    const int lane = tid & 63, wave = tid >> 6;
    __shared__ float red[4];
    const unsigned short* row = Wht + (long)m * 1024;
    float s = 0.0f;
#pragma unroll
    for (int k = 0; k < 4; ++k) {
        const int idx = tid * 4 + k;
        s += bf2f(row[idx]) * bv[idx];
    }
    for (int o = 32; o > 0; o >>= 1) s += __shfl_down(s, o);
    if (lane == 0) red[wave] = s;
    __syncthreads();
    if (tid == 0) bhh[m] = red[0] + red[1] + red[2] + red[3] + bh[m];
}

// ---------------------------------------------------------------------------
// prep: x cast [0,8192) | Wv plain cast [8192,9216) |
//       transposes Wq/Wk/Wh [9216,12288) | biases + sums-zero [12288]
// ---------------------------------------------------------------------------
__global__ void prep(const float* __restrict__ x,
                     const float* __restrict__ Wq, const float* __restrict__ Wk,
                     const float* __restrict__ Wv, const float* __restrict__ Wh,
                     const float* __restrict__ bq, const float* __restrict__ bk,
                     unsigned short* __restrict__ Xbf,
                     unsigned short* __restrict__ Wqkvt,
                     unsigned short* __restrict__ Wht,
                     unsigned short* __restrict__ Wvb,
                     float* __restrict__ bqkv,
                     float* __restrict__ sums)
{
    __shared__ unsigned short tsh[32][33];
    const int bid = blockIdx.x;
    const int tid = threadIdx.x;

    if (bid < 8192) {                       // cast x
        const int i = bid * 256 + tid;
        f4 v = ((const f4*)x)[i];
        unsigned long long p = (unsigned long long)f2bf(v.x)
                             | ((unsigned long long)f2bf(v.y) << 16)
                             | ((unsigned long long)f2bf(v.z) << 32)
                             | ((unsigned long long)f2bf(v.w) << 48);
        ((unsigned long long*)Xbf)[i] = p;
    } else if (bid < 9216) {                // plain cast Wv
        const int i = (bid - 8192) * 256 + tid;
        f4 v = ((const f4*)Wv)[i];
        unsigned long long p = (unsigned long long)f2bf(v.x)
                             | ((unsigned long long)f2bf(v.y) << 16)
                             | ((unsigned long long)f2bf(v.z) << 32)
                             | ((unsigned long long)f2bf(v.w) << 48);
        ((unsigned long long*)Wvb)[i] = p;
    } else if (bid < 12288) {               // transpose+cast Wq, Wk, Wh
        const int wi = bid - 9216;
        const int w = wi >> 10, tile = wi & 1023;
        const float* src = (w == 0) ? Wq : (w == 1) ? Wk : Wh;
        unsigned short* dst = (w == 0) ? Wqkvt : (w == 1) ? (Wqkvt + 1024 * 1024) : Wht;
        const int c0 = (tile & 31) * 32, r0 = (tile >> 5) * 32;
        const int xx = tid & 31, yy = tid >> 5;
        for (int i = yy; i < 32; i += 8)
            tsh[i][xx] = f2bf(src[(long)(r0 + i) * 1024 + c0 + xx]);
        __syncthreads();
        for (int i = yy; i < 32; i += 8)
            dst[(long)(c0 + i) * 1024 + r0 + xx] = tsh[xx][i];
    } else {                                // biases + zero the row-sum acc
        const int i = (bid - 12288) * 256 + tid;
        if (i < 1024) { bqkv[i] = bq[i]; bqkv[1024 + i] = bk[i]; bqkv[2048 + i] = 0.0f; }
        for (int k = tid; k < 8192; k += 256) sums[k] = 0.0f;
    }
}

// ---------------------------------------------------------------------------
extern "C" void kernel_launch(void* const* d_in, const int* in_sizes, int n_in,
                              void* d_out, int out_size, void* d_ws, size_t ws_size,
                              hipStream_t stream)
{
    const float* x  = (const float*)d_in[0];
    const float* Wq = (const float*)d_in[1];
    const float* bq = (const float*)d_in[2];
    const float* Wk = (const float*)d_in[3];
    const float* bk = (const float*)d_in[4];
    const float* Wv = (const float*)d_in[5];
    const float* bv = (const float*)d_in[6];
    const float* Wh = (const float*)d_in[7];
    const float* bh = (const float*)d_in[8];
    float* out = (float*)d_out;

    const int  Bb = 4, T = 2048, Dm = 1024;
    const long BT = (long)Bb * T;

    unsigned short* ws = (unsigned short*)d_ws;
    size_t o = 0;
    unsigned short* Xbf   = ws + o; o += (size_t)BT * Dm;         // 16 MB
    unsigned short* Wqkvt = ws + o; o += (size_t)3 * Dm * Dm;     //  6 MB (3rd = Wvh^T)
    unsigned short* Wht   = ws + o; o += (size_t)Dm * Dm;         //  2 MB
    unsigned short* Wvb   = ws + o; o += (size_t)Dm * Dm;         //  2 MB
    float* bqkv = (float*)(ws + o); o += (size_t)3 * Dm * 2;      // 12 KB
    float* bhh  = (float*)(ws + o); o += (size_t)Dm * 2;          //  4 KB
    float* sums = (float*)(ws + o); o += (size_t)BT * 2;          // 32 KB
    unsigned short* QKV   = ws + o; o += (size_t)BT * 3 * Dm;     // 48 MB
    unsigned short* Vt    = ws + o; o += (size_t)BT * Dm;         // 16 MB (Vh^T)
    unsigned short* Pp    = ws + o; o += (size_t)Bb * T * T;      // 32 MB (P' = exp(s))
    float* part = (float*)(ws + o);                               // 32 MB fp32 partial

    const dim3 blk(256);
    const dim3 blk2(512);
    const long sRow3 = (long)T * 3 * Dm;

    // 1. prep: casts, transposes, biases, sums-zero (memset folded in)
    prep<<<12289, blk, 0, stream>>>(x, Wq, Wk, Wv, Wh, bq, bk,
                                    Xbf, Wqkvt, Wht, Wvb, bqkv, sums);

    // 2a. Wvh^T = (Wv@Wh)^T : C[m][n] = sum_k Wht[m][k]*Wvb[n][k] -> bf16
    gemm_bt<F_OBF><<<dim3(Dm / BN, Dm / BM, 1), blk, 0, stream>>>(
        Wht, Wvb, Wqkvt + 2 * Dm * Dm, nullptr, Dm, Dm, Dm, Dm, Dm, Dm,
        0, 0, 0, 1.0f, nullptr, 0, 0, 0, nullptr);

    // 2b. bhh = bv@Wh + bh
    gemv_bhh<<<Dm, blk, 0, stream>>>(Wht, bv, bh, bhh);

    // 3a. Q,K projection: 256^2 core; grid (8,32) = 256 blocks = EXACTLY
    //     1.0 round. Writes cols [0,2048) of QKV (ldc=3072). <8,32> swizzle.
    gemm256<F_OBF, 8, 32>
        <<<dim3(2 * Dm / BN2, BT / BM2, 1), blk2, 0, stream>>>(
        Xbf, Wqkvt, QKV, bqkv, (int)BT, 2 * Dm, Dm, Dm, Dm, 3 * Dm,
        0, 0, 0, 1.0f, nullptr, 0, 0, 0, nullptr);

    // 3b. Vh = x@(Wv@Wh) written TRANSPOSED into Vt: 128x256 core; grid
    //     (4,64) = 256 blocks = EXACTLY 1.0 round. vsplit=0 -> all blocks
    //     take the Vt path. Vh bias is zero -> nullptr. <4,64> swizzle.
    gemmw<F_OBF | F_VSPL, 4, 64>
        <<<dim3(Dm / BN3, BT / BM3, 1), blk2, 0, stream>>>(
        Xbf, Wqkvt + 2 * Dm * Dm, QKV, nullptr, (int)BT, Dm, Dm, Dm, Dm, 3 * Dm,
        0, 0, 0, 1.0f, Vt, (long)Dm * T, T, 0, nullptr);

    // 4. S^T = exp(K@Q^T / 32) * mask(s<=t), packed 8B stores -> Pp[t][s],
    //    per-col (t) rowsums. A=K, Bt=Q (operand swap = F_TRS). grid
    //    (8,8,Bb), <8,8> swizzle; 36 active tiles/batch (skip m0>n0+255).
    gemm256<F_OBF | F_SKIP | F_EXP | F_RSUM | F_TRS, 8, 8>
        <<<dim3(T / BN2, T / BM2, Bb), blk2, 0, stream>>>(
        QKV + Dm, QKV, Pp, nullptr, T, T, Dm, 3 * Dm, 3 * Dm, T,
        sRow3, sRow3, (long)T * T, 1.0f / 32.0f,
        nullptr, 0, 0, 0, sums);

    // 5. out = (P' @ Vh^T) * (1/sums[row]) + bhh, split-K2 (split1 -> part);
    //    reciprocal computed inline in the epilogue (recip_sums folded in).
    //    grid (8, 8, Bb) == <GX=8, GY=8> SALU XCD swizzle
    gemm256<F_KLIM | F_REVY | F_RSCL | F_SPLITK, 8, 8>
        <<<dim3(2 * Dm / BN2, T / BM2, Bb), blk2, 0, stream>>>(
        Pp, Vt, out, bhh, T, Dm, T, T, T, Dm,
        (long)T * T, (long)Dm * T, (long)T * Dm, 1.0f,
        (unsigned short*)part, 0, 0, 0, sums);

    // 6. out upper rows += part upper rows
    combine_upper<<<dim3(1024, Bb), blk, 0, stream>>>(out, part);
}